// Round 6
// baseline (514.578 us; speedup 1.0000x reference)
//
#include <hip/hip_runtime.h>

#define E_DIM  256
#define N_E    16384
#define N_ROWS 8192
#define HW     1024
#define NPART  16           // n-groups of 1024 cols

typedef _Float16 f16x8 __attribute__((ext_vector_type(8)));
typedef float    f32x4 __attribute__((ext_vector_type(4)));

#define ESCALE   1048576.0f          // 2^20 (exact)
#define UNSCALE  1.9073486328125e-6f // 2^-19: acc*2^-19 == 2*dot

// async 16B global->LDS copy: HW writes lds_base + lane*16; pass wave-uniform lds base
__device__ __forceinline__ void gld_lds16(_Float16* lds, const _Float16* g) {
  __builtin_amdgcn_global_load_lds(
      (__attribute__((address_space(1))) void*)(g),
      (__attribute__((address_space(3))) void*)(lds), 16, 0, 0);
}

// ---------- prep: E -> fragment-major fp16 limbs + ||e||^2 (numpy pairwise) ----------
// Bf layout per limb: [kc][colgrp=k>>4][lane=q*16+(k&15)][8 f16]  (16B per lane)
// task per (row, half): gid = k*2+h; halves combined via shfl_xor(1) -> exact fl(h0+h1)
__global__ __launch_bounds__(128) void k_e_prep(const float* __restrict__ E,
                                                _Float16* __restrict__ Bf0,
                                                _Float16* __restrict__ Bf1,
                                                float* __restrict__ eNorm,
                                                float* __restrict__ out_loss) {
#pragma clang fp contract(off)
  int gid = blockIdx.x * 128 + threadIdx.x;
  int k = gid >> 1, h = gid & 1;
  if (gid == 0) out_loss[0] = 0.f;   // stream-ordered before k_post's atomics
  const float* p = E + (size_t)k * E_DIM + h * 128;
  float r[8] = {0.f, 0.f, 0.f, 0.f, 0.f, 0.f, 0.f, 0.f};
  for (int i = 0; i < 128; i += 8) {
    float4 v0 = *(const float4*)&p[i];
    float4 v1 = *(const float4*)&p[i + 4];
    float v[8] = {v0.x, v0.y, v0.z, v0.w, v1.x, v1.y, v1.z, v1.w};
    f16x8 hh, ll;
#pragma unroll
    for (int j = 0; j < 8; ++j) {
      r[j] = r[j] + v[j] * v[j];
      float s = v[j] * ESCALE;
      _Float16 hi = (_Float16)s;
      hh[j] = hi;
      ll[j] = (_Float16)(s - (float)hi);
    }
    int c = h * 128 + i;                 // GEMM-k position (multiple of 8)
    int kc = c >> 5, q = (c >> 3) & 3;
    size_t dst = (size_t)kc * (N_E * 32) + (size_t)(k >> 4) * 512
               + (size_t)(q * 16 + (k & 15)) * 8;
    *(f16x8*)&Bf0[dst] = hh;
    *(f16x8*)&Bf1[dst] = ll;
  }
  float half = ((r[0] + r[1]) + (r[2] + r[3])) + ((r[4] + r[5]) + (r[6] + r[7]));
  float other = __shfl_xor(half, 1, 64);
  if (h == 0) eNorm[k] = half + other;   // fl(halves[0]+halves[1])
}

// ---------- prep: z (b,c,hw) -> kc-tiled XOR-swizzled limbs + ||z||^2 ----------
// Ah/Al[kc][n][32], 16B block q stored at q^((n>>1)&3) (round-4-verified layout)
__global__ __launch_bounds__(128) void k_z_prep(const float* __restrict__ z,
                                                _Float16* __restrict__ Ah,
                                                _Float16* __restrict__ Al,
                                                float* __restrict__ zNorm) {
#pragma clang fp contract(off)
  int gid = blockIdx.x * 128 + threadIdx.x;
  int n = gid >> 1, h = gid & 1;
  int b = n >> 10, hw = n & 1023;
  const float* a = z + ((size_t)b * E_DIM + h * 128) * HW + hw;
  const int perm = (n >> 1) & 3;
  float r[8] = {0.f, 0.f, 0.f, 0.f, 0.f, 0.f, 0.f, 0.f};
  for (int i = 0; i < 128; i += 8) {
    f16x8 hh, ll;
#pragma unroll
    for (int j = 0; j < 8; ++j) {
      float v = a[(size_t)(i + j) * HW];
      r[j] = r[j] + v * v;
      _Float16 hi = (_Float16)v;
      hh[j] = hi;
      ll[j] = (_Float16)(v - (float)hi);
    }
    int c = h * 128 + i;
    int kc = c >> 5, q = (c >> 3) & 3;
    size_t dst = (size_t)kc * (N_ROWS * 32) + (size_t)n * 32 + (size_t)(q ^ perm) * 8;
    *(f16x8*)&Ah[dst] = hh;
    *(f16x8*)&Al[dst] = ll;
  }
  float half = ((r[0] + r[1]) + (r[2] + r[3])) + ((r[4] + r[5]) + (r[6] + r[7]));
  float other = __shfl_xor(half, 1, 64);
  if (h == 0) zNorm[n] = half + other;
}

// ---------- main: barrier-free K-loop. A resident in LDS; B direct global->reg ----------
// grid (128 mt, 16 ng); block 256 = 4 waves sharing 64 A-rows, each wave owns a 64-col slice
__global__ __launch_bounds__(256, 2) void k_scores_mfma(
    const _Float16* __restrict__ Ah, const _Float16* __restrict__ Al,
    const _Float16* __restrict__ Bf0, const _Float16* __restrict__ Bf1,
    const float* __restrict__ eNorm, const float* __restrict__ zNorm,
    float* __restrict__ pVal, int* __restrict__ pIdx) {
#pragma clang fp contract(off)
  __shared__ alignas(16) _Float16 As[2][8][64][32];  // 64 KB, full A tile (swizzled)
  __shared__ float zNl[64];
  __shared__ float sV[256];
  __shared__ int   sI[256];

  const int mt = blockIdx.x, ng = blockIdx.y;
  const int m0 = mt * 64;
  const int t = threadIdx.x;
  const int lane = t & 63, w = t >> 6;
  const int tx = lane & 15, quad = lane >> 4;
  const int swz = (quad ^ ((tx >> 1) & 3)) * 8;

  // ---- stage full A once: wave w -> limb w>>1, kc-range (w&1)*4.. ----
  {
    const _Float16* src = (w >> 1) ? Al : Ah;
    _Float16* dstb = &As[w >> 1][0][0][0];
    const int kc0 = (w & 1) * 4;
#pragma unroll
    for (int kk = 0; kk < 4; ++kk) {
      const int kc = kc0 + kk;
      const _Float16* g = src + (size_t)kc * (N_ROWS * 32) + (size_t)m0 * 32 + lane * 8;
      _Float16* l = dstb + kc * 2048;
#pragma unroll
      for (int c = 0; c < 4; ++c)
        gld_lds16(l + c * 512, g + c * 512);
    }
  }
  if (t < 64) zNl[t] = zNorm[m0 + t];
  __syncthreads();   // the ONLY barrier before the epilogue

  float runv[16];
  int   runc[16];
#pragma unroll
  for (int q2 = 0; q2 < 16; ++q2) { runv[q2] = 3.4e38f; runc[q2] = 0x7fffffff; }

  const size_t bplane = (size_t)N_E * 32;

  for (int it = 0; it < 4; ++it) {
    const int ncol0 = ng * 1024 + it * 256 + w * 64;
    const size_t gb = (size_t)(ncol0 >> 4) * 512 + (size_t)lane * 8;

    f32x4 acc[4][4];
#pragma unroll
    for (int i = 0; i < 4; ++i)
#pragma unroll
      for (int j = 0; j < 4; ++j) acc[i][j] = (f32x4){0.f, 0.f, 0.f, 0.f};

    for (int kc = 0; kc < 8; ++kc) {
      f16x8 bh[4], bl[4];
#pragma unroll
      for (int j = 0; j < 4; ++j) {
        bh[j] = *(const f16x8*)&Bf0[(size_t)kc * bplane + gb + j * 512];
        bl[j] = *(const f16x8*)&Bf1[(size_t)kc * bplane + gb + j * 512];
      }
      f16x8 ah[4], al[4];
#pragma unroll
      for (int i = 0; i < 4; ++i) {
        ah[i] = *(const f16x8*)&As[0][kc][i * 16 + tx][swz];
        al[i] = *(const f16x8*)&As[1][kc][i * 16 + tx][swz];
      }
#pragma unroll
      for (int i = 0; i < 4; ++i)
#pragma unroll
        for (int j = 0; j < 4; ++j) {
          acc[i][j] = __builtin_amdgcn_mfma_f32_16x16x32_f16(ah[i], bh[j], acc[i][j], 0, 0, 0);
          acc[i][j] = __builtin_amdgcn_mfma_f32_16x16x32_f16(ah[i], bl[j], acc[i][j], 0, 0, 0);
          acc[i][j] = __builtin_amdgcn_mfma_f32_16x16x32_f16(al[i], bh[j], acc[i][j], 0, 0, 0);
        }
    }

    // running score/argmin (cols ascend with it, j -> strict < keeps lowest col)
    float en[4];
#pragma unroll
    for (int j = 0; j < 4; ++j) en[j] = eNorm[ncol0 + j * 16 + tx];
#pragma unroll
    for (int i = 0; i < 4; ++i) {
#pragma unroll
      for (int r = 0; r < 4; ++r) {
        const float zn = zNl[i * 16 + quad * 4 + r];
        const int q2 = i * 4 + r;
#pragma unroll
        for (int j = 0; j < 4; ++j) {
          float s = (zn + en[j]) - acc[i][j][r] * UNSCALE;
          if (s < runv[q2]) { runv[q2] = s; runc[q2] = ncol0 + j * 16 + tx; }
        }
      }
    }
  }

  // ---- reduce: shfl over tx, then cross-wave lexicographic combine via LDS ----
#pragma unroll
  for (int i = 0; i < 4; ++i) {
#pragma unroll
    for (int r = 0; r < 4; ++r) {
      const int q2 = i * 4 + r;
      float bv = runv[q2];
      int bc = runc[q2];
#pragma unroll
      for (int off = 1; off < 16; off <<= 1) {
        float ov = __shfl_xor(bv, off, 64);
        int oc = __shfl_xor(bc, off, 64);
        if (ov < bv || (ov == bv && oc < bc)) { bv = ov; bc = oc; }
      }
      if (tx == 0) {
        const int row = i * 16 + quad * 4 + r;
        sV[w * 64 + row] = bv;
        sI[w * 64 + row] = bc;
      }
    }
  }
  __syncthreads();
  if (t < 64) {
    float mv = sV[t];
    int mi = sI[t];
#pragma unroll
    for (int ww = 1; ww < 4; ++ww) {
      float v = sV[ww * 64 + t];
      int id = sI[ww * 64 + t];
      if (v < mv || (v == mv && id < mi)) { mv = v; mi = id; }
    }
    pVal[(size_t)ng * N_ROWS + m0 + t] = mv;
    pIdx[(size_t)ng * N_ROWS + m0 + t] = mi;
  }
}

// ---------- fused: final argmin (16 partials) + gather z_q + loss ----------
// 2 threads per row (h = channel half); both scan partials redundantly.
__global__ __launch_bounds__(128) void k_post(const float* __restrict__ pVal,
                                              const int* __restrict__ pIdx,
                                              const float* __restrict__ z,
                                              const float* __restrict__ E,
                                              float* __restrict__ out,
                                              float* __restrict__ out_loss,
                                              float* __restrict__ out_idx) {
  int t = threadIdx.x;
  int n = blockIdx.x * 64 + (t & 63);
  int h = t >> 6;
  float mv = 3.4e38f;
  int mi = 0x7fffffff;
#pragma unroll
  for (int s2 = 0; s2 < NPART; ++s2) {
    float v = pVal[(size_t)s2 * N_ROWS + n];
    int id = pIdx[(size_t)s2 * N_ROWS + n];
    if (v < mv || (v == mv && id < mi)) { mv = v; mi = id; }
  }
  if (h == 0) out_idx[n] = (float)mi;

  int b = n >> 10, hw = n & 1023;
  const float4* erow4 = (const float4*)(E + (size_t)mi * E_DIM + h * 128);
  const float* zrow = z + ((size_t)b * E_DIM + h * 128) * HW + hw;
  float* orow = out + ((size_t)b * E_DIM + h * 128) * HW + hw;
  float s = 0.f;
  for (int c4 = 0; c4 < 32; ++c4) {
    float4 e4 = erow4[c4];
    float ev[4] = {e4.x, e4.y, e4.z, e4.w};
#pragma unroll
    for (int j2 = 0; j2 < 4; ++j2) {
      int c = c4 * 4 + j2;
      float zv = zrow[(size_t)c * HW];
      orow[(size_t)c * HW] = ev[j2];
      float d = ev[j2] - zv;
      s = fmaf(d, d, s);
    }
  }
  for (int off = 32; off > 0; off >>= 1) s += __shfl_down(s, off, 64);
  __shared__ float wsum[2];
  if ((t & 63) == 0) wsum[t >> 6] = s;
  __syncthreads();
  if (t == 0) atomicAdd(out_loss, (wsum[0] + wsum[1]) * (1.25f / 2097152.f));
}

extern "C" void kernel_launch(void* const* d_in, const int* in_sizes, int n_in,
                              void* d_out, int out_size, void* d_ws, size_t ws_size,
                              hipStream_t stream) {
  const float* z = (const float*)d_in[0];
  const float* E = (const float*)d_in[1];
  float* out = (float*)d_out;
  float* out_loss = out + 2097152;  // after z_q (8*256*32*32)
  float* out_idx = out + 2097153;

  // workspace (~26 MB): Ah|Al f16[8][8192][32], Bf0|Bf1 f16 fragment-major [8][1024][512],
  //                     eNorm, zNorm, pVal[16][8192], pIdx[16][8192]
  _Float16* Ah = (_Float16*)d_ws;
  _Float16* Al = Ah + (size_t)N_ROWS * E_DIM;
  _Float16* Bf0 = Al + (size_t)N_ROWS * E_DIM;
  _Float16* Bf1 = Bf0 + (size_t)N_E * E_DIM;
  float* eNorm = (float*)(Bf1 + (size_t)N_E * E_DIM);
  float* zNorm = eNorm + N_E;
  float* pVal = zNorm + N_ROWS;
  int* pIdx = (int*)(pVal + (size_t)NPART * N_ROWS);

  k_e_prep<<<(N_E * 2) / 128, 128, 0, stream>>>(E, Bf0, Bf1, eNorm, out_loss);
  k_z_prep<<<(N_ROWS * 2) / 128, 128, 0, stream>>>(z, Ah, Al, zNorm);
  k_scores_mfma<<<dim3(N_ROWS / 64, NPART), 256, 0, stream>>>(
      Ah, Al, Bf0, Bf1, eNorm, zNorm, pVal, pIdx);
  k_post<<<N_ROWS / 64, 128, 0, stream>>>(pVal, pIdx, z, E, out, out_loss, out_idx);
}

// Round 7
// 361.226 us; speedup vs baseline: 1.4245x; 1.4245x over previous
//
#include <hip/hip_runtime.h>

#define E_DIM  256
#define N_E    16384
#define N_ROWS 8192
#define HW     1024
#define NPART  128          // n-tiles of 128 cols

typedef _Float16 f16x8 __attribute__((ext_vector_type(8)));
typedef float    f32x4 __attribute__((ext_vector_type(4)));

#define ESCALE   1048576.0f          // 2^20 (exact)
#define UNSCALE  1.9073486328125e-6f // 2^-19: acc*2^-19 == 2*dot

// async 16B global->LDS copy: HW writes lds_base + lane*16 (wave-uniform base)
__device__ __forceinline__ void gld_lds16(_Float16* lds, const _Float16* g) {
  __builtin_amdgcn_global_load_lds(
      (__attribute__((address_space(1))) void*)(g),
      (__attribute__((address_space(3))) void*)(lds), 16, 0, 0);
}

// ---------- prep: E -> kc-tiled XOR-swizzled fp16 limbs + ||e||^2 (numpy pairwise) ----------
// layout: Bh/Bl[kc][k][32 f16], 16B block q stored at physical block q^((k>>1)&3)
// task per (row, half): gid = k*2+h; halves combined via shfl_xor(1) -> exact fl(h0+h1)
__global__ __launch_bounds__(128) void k_e_prep(const float* __restrict__ E,
                                                _Float16* __restrict__ Bh,
                                                _Float16* __restrict__ Bl,
                                                float* __restrict__ eNorm,
                                                float* __restrict__ out_loss) {
#pragma clang fp contract(off)
  int gid = blockIdx.x * 128 + threadIdx.x;
  int k = gid >> 1, h = gid & 1;
  if (gid == 0) out_loss[0] = 0.f;   // stream-ordered before k_post's atomics
  const float* p = E + (size_t)k * E_DIM + h * 128;
  const int perm = (k >> 1) & 3;
  float r[8] = {0.f, 0.f, 0.f, 0.f, 0.f, 0.f, 0.f, 0.f};
  for (int i = 0; i < 128; i += 8) {
    float4 v0 = *(const float4*)&p[i];
    float4 v1 = *(const float4*)&p[i + 4];
    float v[8] = {v0.x, v0.y, v0.z, v0.w, v1.x, v1.y, v1.z, v1.w};
    f16x8 hh, ll;
#pragma unroll
    for (int j = 0; j < 8; ++j) {
      r[j] = r[j] + v[j] * v[j];
      float s = v[j] * ESCALE;
      _Float16 hi = (_Float16)s;
      hh[j] = hi;
      ll[j] = (_Float16)(s - (float)hi);
    }
    int c = h * 128 + i;                 // GEMM-k position (multiple of 8)
    int kc = c >> 5, q = (c >> 3) & 3;
    size_t dst = (size_t)kc * (N_E * 32) + (size_t)k * 32 + (size_t)(q ^ perm) * 8;
    *(f16x8*)&Bh[dst] = hh;
    *(f16x8*)&Bl[dst] = ll;
  }
  float half = ((r[0] + r[1]) + (r[2] + r[3])) + ((r[4] + r[5]) + (r[6] + r[7]));
  float other = __shfl_xor(half, 1, 64);
  if (h == 0) eNorm[k] = half + other;   // fl(halves[0]+halves[1])
}

// ---------- prep: z (b,c,hw) -> kc-tiled XOR-swizzled limbs + ||z||^2 ----------
__global__ __launch_bounds__(128) void k_z_prep(const float* __restrict__ z,
                                                _Float16* __restrict__ Ah,
                                                _Float16* __restrict__ Al,
                                                float* __restrict__ zNorm) {
#pragma clang fp contract(off)
  int gid = blockIdx.x * 128 + threadIdx.x;
  int n = gid >> 1, h = gid & 1;
  int b = n >> 10, hw = n & 1023;
  const float* a = z + ((size_t)b * E_DIM + h * 128) * HW + hw;
  const int perm = (n >> 1) & 3;
  float r[8] = {0.f, 0.f, 0.f, 0.f, 0.f, 0.f, 0.f, 0.f};
  for (int i = 0; i < 128; i += 8) {
    f16x8 hh, ll;
#pragma unroll
    for (int j = 0; j < 8; ++j) {
      float v = a[(size_t)(i + j) * HW];
      r[j] = r[j] + v * v;
      _Float16 hi = (_Float16)v;
      hh[j] = hi;
      ll[j] = (_Float16)(v - (float)hi);
    }
    int c = h * 128 + i;
    int kc = c >> 5, q = (c >> 3) & 3;
    size_t dst = (size_t)kc * (N_ROWS * 32) + (size_t)n * 32 + (size_t)(q ^ perm) * 8;
    *(f16x8*)&Ah[dst] = hh;
    *(f16x8*)&Al[dst] = ll;
  }
  float half = ((r[0] + r[1]) + (r[2] + r[3])) + ((r[4] + r[5]) + (r[6] + r[7]));
  float other = __shfl_xor(half, 1, 64);
  if (h == 0) zNorm[n] = half + other;
}

// ---------- main: 3-pass fp16-limb MFMA GEMM, block 128x128, wave 64x64 ----------
// Round-4 kernel verbatim (proven: 247 us, MfmaUtil 37.8%, VGPR 68, 0 conflicts)
__global__ __launch_bounds__(256, 3) void k_scores_mfma(
    const _Float16* __restrict__ Ah, const _Float16* __restrict__ Al,
    const _Float16* __restrict__ Bh, const _Float16* __restrict__ Bl,
    const float* __restrict__ eNorm, const float* __restrict__ zNorm,
    float* __restrict__ pVal, int* __restrict__ pIdx) {
#pragma clang fp contract(off)
  __shared__ alignas(16) _Float16 As[2][128][32];  // 16 KB: limb, row, swizzled 32 f16
  __shared__ alignas(16) _Float16 Bs[2][128][32];  // 16 KB

  const int mt = blockIdx.x, nt = blockIdx.y;
  const int m0 = mt * 128, n0 = nt * 128;

  const int t = threadIdx.x;
  const int lane = t & 63, w = t >> 6;
  const int tx = lane & 15, quad = lane >> 4;
  const int wm = (w >> 1) * 64, wn = (w & 1) * 64;
  const int swz = (quad ^ ((tx >> 1) & 3)) * 8;    // physical f16 offset of logical block

  // per-wave staging segment (8 KB contiguous per kc-slab)
  const _Float16* gseg;
  size_t plane;
  _Float16* lseg;
  if (w == 0)      { gseg = Ah + (size_t)m0 * 32; plane = (size_t)N_ROWS * 32; lseg = &As[0][0][0]; }
  else if (w == 1) { gseg = Al + (size_t)m0 * 32; plane = (size_t)N_ROWS * 32; lseg = &As[1][0][0]; }
  else if (w == 2) { gseg = Bh + (size_t)n0 * 32; plane = (size_t)N_E * 32;    lseg = &Bs[0][0][0]; }
  else             { gseg = Bl + (size_t)n0 * 32; plane = (size_t)N_E * 32;    lseg = &Bs[1][0][0]; }

  f32x4 acc[4][4];
#pragma unroll
  for (int i = 0; i < 4; ++i)
#pragma unroll
    for (int j = 0; j < 4; ++j) acc[i][j] = (f32x4){0.f, 0.f, 0.f, 0.f};

  for (int kc = 0; kc < 8; ++kc) {
    __syncthreads();                       // previous iteration's frag reads done
    const _Float16* g = gseg + (size_t)kc * plane + lane * 8;
#pragma unroll
    for (int c = 0; c < 8; ++c)
      gld_lds16(lseg + c * 512, g + c * 512);   // 8 x 1KB async copies per wave
    __syncthreads();                       // vmcnt(0) drained before barrier -> data visible

    f16x8 bh[4], bl[4];
#pragma unroll
    for (int j = 0; j < 4; ++j) {
      bh[j] = *(const f16x8*)&Bs[0][wn + j * 16 + tx][swz];
      bl[j] = *(const f16x8*)&Bs[1][wn + j * 16 + tx][swz];
    }
#pragma unroll
    for (int i = 0; i < 4; ++i) {
      f16x8 ah = *(const f16x8*)&As[0][wm + i * 16 + tx][swz];
      f16x8 al = *(const f16x8*)&As[1][wm + i * 16 + tx][swz];
#pragma unroll
      for (int j = 0; j < 4; ++j) {
        acc[i][j] = __builtin_amdgcn_mfma_f32_16x16x32_f16(ah, bh[j], acc[i][j], 0, 0, 0);
        acc[i][j] = __builtin_amdgcn_mfma_f32_16x16x32_f16(ah, bl[j], acc[i][j], 0, 0, 0);
        acc[i][j] = __builtin_amdgcn_mfma_f32_16x16x32_f16(al, bh[j], acc[i][j], 0, 0, 0);
      }
    }
  }

  // ---- epilogue: score + argmin (first-index tie-break) ----
  __syncthreads();
  float* sF  = (float*)&As[0][0][0];
  float* zNl = sF;                 // [128]
  float* eNl = sF + 128;           // [128]
  float* sV  = sF + 256;           // [2][128]
  int*   sI  = (int*)(sF + 512);   // [2][128]
  if (t < 128) zNl[t] = zNorm[m0 + t];
  else         eNl[t - 128] = eNorm[n0 + t - 128];
  __syncthreads();

#pragma unroll
  for (int i = 0; i < 4; ++i) {
#pragma unroll
    for (int r = 0; r < 4; ++r) {
      const int rloc = wm + i * 16 + quad * 4 + r;
      const float zn = zNl[rloc];
      float bv = 3.4e38f;
      int bc = 0x7fffffff;
#pragma unroll
      for (int j = 0; j < 4; ++j) {
        const int col = wn + j * 16 + tx;
        float s = (zn + eNl[col]) - acc[i][j][r] * UNSCALE;
        if (s < bv) { bv = s; bc = n0 + col; }   // j ascending: strict < keeps lowest col
      }
#pragma unroll
      for (int off = 1; off < 16; off <<= 1) {
        float ov = __shfl_xor(bv, off, 64);
        int oc = __shfl_xor(bc, off, 64);
        if (ov < bv || (ov == bv && oc < bc)) { bv = ov; bc = oc; }
      }
      if (tx == 0) { sV[(w & 1) * 128 + rloc] = bv; sI[(w & 1) * 128 + rloc] = bc; }
    }
  }
  __syncthreads();
  if (t < 128) {
    float v0 = sV[t], v1 = sV[128 + t];
    int i0 = sI[t], i1 = sI[128 + t];
    int take1 = (v1 < v0) || (v1 == v0 && i1 < i0);
    pVal[(size_t)nt * N_ROWS + m0 + t] = take1 ? v1 : v0;
    pIdx[(size_t)nt * N_ROWS + m0 + t] = take1 ? i1 : i0;
  }
}

// ---------- fused: final argmin (128 partials) + gather z_q + loss ----------
// 2 threads per row (h = channel half); both scan partials redundantly (exact: pair-min assoc).
__global__ __launch_bounds__(128) void k_post(const float* __restrict__ pVal,
                                              const int* __restrict__ pIdx,
                                              const float* __restrict__ z,
                                              const float* __restrict__ E,
                                              float* __restrict__ out,
                                              float* __restrict__ out_loss,
                                              float* __restrict__ out_idx) {
  int t = threadIdx.x;
  int n = blockIdx.x * 64 + (t & 63);
  int h = t >> 6;
  float mv = 3.4e38f;
  int mi = 0x7fffffff;
  for (int s2 = 0; s2 < NPART; ++s2) {
    float v = pVal[(size_t)s2 * N_ROWS + n];
    int id = pIdx[(size_t)s2 * N_ROWS + n];
    if (v < mv || (v == mv && id < mi)) { mv = v; mi = id; }
  }
  if (h == 0) out_idx[n] = (float)mi;

  int b = n >> 10, hw = n & 1023;
  const float4* erow4 = (const float4*)(E + (size_t)mi * E_DIM + h * 128);
  const float* zrow = z + ((size_t)b * E_DIM + h * 128) * HW + hw;
  float* orow = out + ((size_t)b * E_DIM + h * 128) * HW + hw;
  float s = 0.f;
  for (int c4 = 0; c4 < 32; ++c4) {
    float4 e4 = erow4[c4];
    float ev[4] = {e4.x, e4.y, e4.z, e4.w};
#pragma unroll
    for (int j2 = 0; j2 < 4; ++j2) {
      int c = c4 * 4 + j2;
      float zv = zrow[(size_t)c * HW];
      orow[(size_t)c * HW] = ev[j2];
      float d = ev[j2] - zv;
      s = fmaf(d, d, s);
    }
  }
  for (int off = 32; off > 0; off >>= 1) s += __shfl_down(s, off, 64);
  __shared__ float wsum[2];
  if ((t & 63) == 0) wsum[t >> 6] = s;
  __syncthreads();
  if (t == 0) atomicAdd(out_loss, (wsum[0] + wsum[1]) * (1.25f / 2097152.f));
}

extern "C" void kernel_launch(void* const* d_in, const int* in_sizes, int n_in,
                              void* d_out, int out_size, void* d_ws, size_t ws_size,
                              hipStream_t stream) {
  const float* z = (const float*)d_in[0];
  const float* E = (const float*)d_in[1];
  float* out = (float*)d_out;
  float* out_loss = out + 2097152;  // after z_q (8*256*32*32)
  float* out_idx = out + 2097153;

  // workspace (~32 MB): Ah|Al f16[8][8192][32], Bh|Bl f16[8][16384][32],
  //                     eNorm, zNorm, pVal[128][8192], pIdx[128][8192]
  _Float16* Ah = (_Float16*)d_ws;
  _Float16* Al = Ah + (size_t)N_ROWS * E_DIM;
  _Float16* Bh = Al + (size_t)N_ROWS * E_DIM;
  _Float16* Bl = Bh + (size_t)N_E * E_DIM;
  float* eNorm = (float*)(Bl + (size_t)N_E * E_DIM);
  float* zNorm = eNorm + N_E;
  float* pVal = zNorm + N_ROWS;
  int* pIdx = (int*)(pVal + (size_t)NPART * N_ROWS);

  k_e_prep<<<(N_E * 2) / 128, 128, 0, stream>>>(E, Bh, Bl, eNorm, out_loss);
  k_z_prep<<<(N_ROWS * 2) / 128, 128, 0, stream>>>(z, Ah, Al, zNorm);
  k_scores_mfma<<<dim3(N_ROWS / 128, N_E / 128), 256, 0, stream>>>(
      Ah, Al, Bh, Bl, eNorm, zNorm, pVal, pIdx);
  k_post<<<N_ROWS / 64, 128, 0, stream>>>(pVal, pIdx, z, E, out, out_loss, out_idx);
}

// Round 8
// 342.774 us; speedup vs baseline: 1.5012x; 1.0538x over previous
//
#include <hip/hip_runtime.h>

#define E_DIM  256
#define N_E    16384
#define N_ROWS 8192
#define HW     1024
#define NPART  128          // n-tiles of 128 cols

typedef _Float16 f16x8 __attribute__((ext_vector_type(8)));
typedef float    f32x4 __attribute__((ext_vector_type(4)));

#define ESCALE   1048576.0f          // 2^20 (exact)
#define UNSCALE  1.9073486328125e-6f // 2^-19: acc*2^-19 == 2*dot

// async 16B global->LDS copy: HW writes lds_base + lane*16 (wave-uniform base)
__device__ __forceinline__ void gld_lds16(_Float16* lds, const _Float16* g) {
  __builtin_amdgcn_global_load_lds(
      (__attribute__((address_space(1))) void*)(g),
      (__attribute__((address_space(3))) void*)(lds), 16, 0, 0);
}

// ---------- fused prep: blockIdx-range dispatch ----------
// [0,2048)    e-limbs  : thread = one 8-elem unit of an E row (fully coalesced)
// [2048,2304) z-limbs  : thread = (row n, kc); lanes hw-minor (coalesced both ways)
// [2304,3328) e-norm   : 16 threads/row, numpy chains + shfl tree (exact order)
// [3328,3840) z-norm   : 16 threads/row, chains + LDS tree (exact order)
#define EB_LIMB 2048
#define ZB_LIMB 256
#define EB_NORM 1024
#define ZB_NORM 512
__global__ __launch_bounds__(256) void k_prep(const float* __restrict__ z,
                                              const float* __restrict__ E,
                                              _Float16* __restrict__ Ah,
                                              _Float16* __restrict__ Al,
                                              _Float16* __restrict__ Bh,
                                              _Float16* __restrict__ Bl,
                                              float* __restrict__ eNorm,
                                              float* __restrict__ zNorm,
                                              float* __restrict__ out_loss) {
#pragma clang fp contract(off)
  __shared__ float sN[16][16];
  const int bi = blockIdx.x, t = threadIdx.x;

  if (bi < EB_LIMB) {
    // ---- e-limbs: gid = k*32 + m; unit m -> (kc=m>>2, q=m&3) ----
    if (bi == 0 && t == 0) out_loss[0] = 0.f;
    int gid = bi * 256 + t;
    int k = gid >> 5, m = gid & 31;
    int kc = m >> 2, q = m & 3;
    const int perm = (k >> 1) & 3;
    float4 v0 = *(const float4*)&E[(size_t)k * E_DIM + m * 8];
    float4 v1 = *(const float4*)&E[(size_t)k * E_DIM + m * 8 + 4];
    float v[8] = {v0.x, v0.y, v0.z, v0.w, v1.x, v1.y, v1.z, v1.w};
    f16x8 hh, ll;
#pragma unroll
    for (int j = 0; j < 8; ++j) {
      float s = v[j] * ESCALE;
      _Float16 hi = (_Float16)s;
      hh[j] = hi;
      ll[j] = (_Float16)(s - (float)hi);
    }
    size_t dst = (size_t)kc * (N_E * 32) + (size_t)k * 32 + (size_t)(q ^ perm) * 8;
    *(f16x8*)&Bh[dst] = hh;
    *(f16x8*)&Bl[dst] = ll;
  } else if (bi < EB_LIMB + ZB_LIMB) {
    // ---- z-limbs: block = 64 rows x 4 kc; lanes hw-minor ----
    int bi2 = bi - EB_LIMB;
    int n0 = (bi2 & 127) * 64;
    int kc = (bi2 >> 7) * 4 + (t >> 6);
    int n = n0 + (t & 63);
    int b = n >> 10, hw = n & 1023;
    const int perm = (n >> 1) & 3;
    const float* zb = z + ((size_t)b * E_DIM + kc * 32) * HW + hw;
#pragma unroll
    for (int q = 0; q < 4; ++q) {
      f16x8 hh, ll;
#pragma unroll
      for (int j = 0; j < 8; ++j) {
        float v = zb[(size_t)(q * 8 + j) * HW];
        _Float16 hi = (_Float16)v;
        hh[j] = hi;
        ll[j] = (_Float16)(v - (float)hi);
      }
      size_t dst = (size_t)kc * (N_ROWS * 32) + (size_t)n * 32 + (size_t)(q ^ perm) * 8;
      *(f16x8*)&Ah[dst] = hh;
      *(f16x8*)&Al[dst] = ll;
    }
  } else if (bi < EB_LIMB + ZB_LIMB + EB_NORM) {
    // ---- e-norm: lane = kq*16 + h*8 + j; chain r_j then shfl tree (numpy order) ----
    int bi2 = bi - (EB_LIMB + ZB_LIMB);
    int lane = t & 63;
    int j = lane & 7, h = (lane >> 3) & 1, kq = lane >> 4;
    int k = bi2 * 16 + (t >> 6) * 4 + kq;
    const float* p = E + (size_t)k * E_DIM + h * 128 + j;
    float r = 0.f;
#pragma unroll
    for (int i = 0; i < 16; ++i) { float v = p[i * 8]; r = r + v * v; }
    r = r + __shfl_xor(r, 1, 64);    // (r0+r1), (r2+r3), ...
    r = r + __shfl_xor(r, 2, 64);    // (r0+r1)+(r2+r3), ...
    r = r + __shfl_xor(r, 4, 64);    // half
    r = r + __shfl_xor(r, 8, 64);    // halves[0]+halves[1]
    if ((lane & 15) == 0) eNorm[k] = r;
  } else {
    // ---- z-norm: nl = t&15 (lane-minor, coalesced); LDS tree in numpy order ----
    int bi2 = bi - (EB_LIMB + ZB_LIMB + EB_NORM);
    int n0 = bi2 * 16;
    int nl = t & 15, c16 = t >> 4;
    int h = c16 >> 3, j = c16 & 7;
    int n = n0 + nl;
    int b = n >> 10, hw = n & 1023;
    const float* p = z + ((size_t)b * E_DIM + h * 128 + j) * HW + hw;
    float r = 0.f;
#pragma unroll
    for (int i = 0; i < 16; ++i) { float v = p[(size_t)i * 8 * HW]; r = r + v * v; }
    sN[nl][c16] = r;
    __syncthreads();
    if (t < 16) {
      const float* q = sN[t];
      float h0 = ((q[0] + q[1]) + (q[2] + q[3])) + ((q[4] + q[5]) + (q[6] + q[7]));
      float h1 = ((q[8] + q[9]) + (q[10] + q[11])) + ((q[12] + q[13]) + (q[14] + q[15]));
      zNorm[n0 + t] = h0 + h1;
    }
  }
}

// ---------- main: 3-pass fp16-limb MFMA GEMM, block 128x128, wave 64x64 ----------
// Proven config: 245 us, MfmaUtil 37.5%, VGPR 68, 0 conflicts (m97-class plateau)
__global__ __launch_bounds__(256, 3) void k_scores_mfma(
    const _Float16* __restrict__ Ah, const _Float16* __restrict__ Al,
    const _Float16* __restrict__ Bh, const _Float16* __restrict__ Bl,
    const float* __restrict__ eNorm, const float* __restrict__ zNorm,
    float* __restrict__ pVal, int* __restrict__ pIdx) {
#pragma clang fp contract(off)
  __shared__ alignas(16) _Float16 As[2][128][32];  // 16 KB: limb, row, swizzled 32 f16
  __shared__ alignas(16) _Float16 Bs[2][128][32];  // 16 KB

  const int mt = blockIdx.x, nt = blockIdx.y;
  const int m0 = mt * 128, n0 = nt * 128;

  const int t = threadIdx.x;
  const int lane = t & 63, w = t >> 6;
  const int tx = lane & 15, quad = lane >> 4;
  const int wm = (w >> 1) * 64, wn = (w & 1) * 64;
  const int swz = (quad ^ ((tx >> 1) & 3)) * 8;    // physical f16 offset of logical block

  const _Float16* gseg;
  size_t plane;
  _Float16* lseg;
  if (w == 0)      { gseg = Ah + (size_t)m0 * 32; plane = (size_t)N_ROWS * 32; lseg = &As[0][0][0]; }
  else if (w == 1) { gseg = Al + (size_t)m0 * 32; plane = (size_t)N_ROWS * 32; lseg = &As[1][0][0]; }
  else if (w == 2) { gseg = Bh + (size_t)n0 * 32; plane = (size_t)N_E * 32;    lseg = &Bs[0][0][0]; }
  else             { gseg = Bl + (size_t)n0 * 32; plane = (size_t)N_E * 32;    lseg = &Bs[1][0][0]; }

  f32x4 acc[4][4];
#pragma unroll
  for (int i = 0; i < 4; ++i)
#pragma unroll
    for (int j = 0; j < 4; ++j) acc[i][j] = (f32x4){0.f, 0.f, 0.f, 0.f};

  for (int kc = 0; kc < 8; ++kc) {
    __syncthreads();                       // previous iteration's frag reads done
    const _Float16* g = gseg + (size_t)kc * plane + lane * 8;
#pragma unroll
    for (int c = 0; c < 8; ++c)
      gld_lds16(lseg + c * 512, g + c * 512);   // 8 x 1KB async copies per wave
    __syncthreads();                       // vmcnt(0) drained before barrier -> data visible

    f16x8 bh[4], bl[4];
#pragma unroll
    for (int j = 0; j < 4; ++j) {
      bh[j] = *(const f16x8*)&Bs[0][wn + j * 16 + tx][swz];
      bl[j] = *(const f16x8*)&Bs[1][wn + j * 16 + tx][swz];
    }
#pragma unroll
    for (int i = 0; i < 4; ++i) {
      f16x8 ah = *(const f16x8*)&As[0][wm + i * 16 + tx][swz];
      f16x8 al = *(const f16x8*)&As[1][wm + i * 16 + tx][swz];
#pragma unroll
      for (int j = 0; j < 4; ++j) {
        acc[i][j] = __builtin_amdgcn_mfma_f32_16x16x32_f16(ah, bh[j], acc[i][j], 0, 0, 0);
        acc[i][j] = __builtin_amdgcn_mfma_f32_16x16x32_f16(ah, bl[j], acc[i][j], 0, 0, 0);
        acc[i][j] = __builtin_amdgcn_mfma_f32_16x16x32_f16(al, bh[j], acc[i][j], 0, 0, 0);
      }
    }
  }

  // ---- epilogue: score + argmin (first-index tie-break) ----
  __syncthreads();
  float* sF  = (float*)&As[0][0][0];
  float* zNl = sF;                 // [128]
  float* eNl = sF + 128;           // [128]
  float* sV  = sF + 256;           // [2][128]
  int*   sI  = (int*)(sF + 512);   // [2][128]
  if (t < 128) zNl[t] = zNorm[m0 + t];
  else         eNl[t - 128] = eNorm[n0 + t - 128];
  __syncthreads();

#pragma unroll
  for (int i = 0; i < 4; ++i) {
#pragma unroll
    for (int r = 0; r < 4; ++r) {
      const int rloc = wm + i * 16 + quad * 4 + r;
      const float zn = zNl[rloc];
      float bv = 3.4e38f;
      int bc = 0x7fffffff;
#pragma unroll
      for (int j = 0; j < 4; ++j) {
        const int col = wn + j * 16 + tx;
        float s = (zn + eNl[col]) - acc[i][j][r] * UNSCALE;
        if (s < bv) { bv = s; bc = n0 + col; }   // j ascending: strict < keeps lowest col
      }
#pragma unroll
      for (int off = 1; off < 16; off <<= 1) {
        float ov = __shfl_xor(bv, off, 64);
        int oc = __shfl_xor(bc, off, 64);
        if (ov < bv || (ov == bv && oc < bc)) { bv = ov; bc = oc; }
      }
      if (tx == 0) { sV[(w & 1) * 128 + rloc] = bv; sI[(w & 1) * 128 + rloc] = bc; }
    }
  }
  __syncthreads();
  if (t < 128) {
    float v0 = sV[t], v1 = sV[128 + t];
    int i0 = sI[t], i1 = sI[128 + t];
    int take1 = (v1 < v0) || (v1 == v0 && i1 < i0);
    pVal[(size_t)nt * N_ROWS + m0 + t] = take1 ? v1 : v0;
    pIdx[(size_t)nt * N_ROWS + m0 + t] = take1 ? i1 : i0;
  }
}

// ---------- fused: final argmin (128 partials) + gather z_q + loss ----------
// 4 threads per row (quarter-channels); all scan partials redundantly (pair-min assoc -> exact)
__global__ __launch_bounds__(256) void k_post(const float* __restrict__ pVal,
                                              const int* __restrict__ pIdx,
                                              const float* __restrict__ z,
                                              const float* __restrict__ E,
                                              float* __restrict__ out,
                                              float* __restrict__ out_loss,
                                              float* __restrict__ out_idx) {
  int t = threadIdx.x;
  int n = blockIdx.x * 64 + (t & 63);
  int h4 = t >> 6;                      // quarter 0..3
  float mv = 3.4e38f;
  int mi = 0x7fffffff;
  for (int s2 = 0; s2 < NPART; ++s2) {
    float v = pVal[(size_t)s2 * N_ROWS + n];
    int id = pIdx[(size_t)s2 * N_ROWS + n];
    if (v < mv || (v == mv && id < mi)) { mv = v; mi = id; }
  }
  if (h4 == 0) out_idx[n] = (float)mi;

  int b = n >> 10, hw = n & 1023;
  const float4* erow4 = (const float4*)(E + (size_t)mi * E_DIM + h4 * 64);
  const float* zrow = z + ((size_t)b * E_DIM + h4 * 64) * HW + hw;
  float* orow = out + ((size_t)b * E_DIM + h4 * 64) * HW + hw;
  float s = 0.f;
  for (int c4 = 0; c4 < 16; ++c4) {
    float4 e4 = erow4[c4];
    float ev[4] = {e4.x, e4.y, e4.z, e4.w};
#pragma unroll
    for (int j2 = 0; j2 < 4; ++j2) {
      int c = c4 * 4 + j2;
      float zv = zrow[(size_t)c * HW];
      orow[(size_t)c * HW] = ev[j2];
      float d = ev[j2] - zv;
      s = fmaf(d, d, s);
    }
  }
  for (int off = 32; off > 0; off >>= 1) s += __shfl_down(s, off, 64);
  __shared__ float wsum[4];
  if ((t & 63) == 0) wsum[t >> 6] = s;
  __syncthreads();
  if (t == 0)
    atomicAdd(out_loss, ((wsum[0] + wsum[1]) + (wsum[2] + wsum[3])) * (1.25f / 2097152.f));
}

extern "C" void kernel_launch(void* const* d_in, const int* in_sizes, int n_in,
                              void* d_out, int out_size, void* d_ws, size_t ws_size,
                              hipStream_t stream) {
  const float* z = (const float*)d_in[0];
  const float* E = (const float*)d_in[1];
  float* out = (float*)d_out;
  float* out_loss = out + 2097152;  // after z_q (8*256*32*32)
  float* out_idx = out + 2097153;

  // workspace (~32 MB): Ah|Al f16[8][8192][32], Bh|Bl f16[8][16384][32],
  //                     eNorm, zNorm, pVal[128][8192], pIdx[128][8192]
  _Float16* Ah = (_Float16*)d_ws;
  _Float16* Al = Ah + (size_t)N_ROWS * E_DIM;
  _Float16* Bh = Al + (size_t)N_ROWS * E_DIM;
  _Float16* Bl = Bh + (size_t)N_E * E_DIM;
  float* eNorm = (float*)(Bl + (size_t)N_E * E_DIM);
  float* zNorm = eNorm + N_E;
  float* pVal = zNorm + N_ROWS;
  int* pIdx = (int*)(pVal + (size_t)NPART * N_ROWS);

  k_prep<<<EB_LIMB + ZB_LIMB + EB_NORM + ZB_NORM, 256, 0, stream>>>(
      z, E, Ah, Al, Bh, Bl, eNorm, zNorm, out_loss);
  k_scores_mfma<<<dim3(N_ROWS / 128, N_E / 128), 256, 0, stream>>>(
      Ah, Al, Bh, Bl, eNorm, zNorm, pVal, pIdx);
  k_post<<<N_ROWS / 64, 256, 0, stream>>>(pVal, pIdx, z, E, out, out_loss, out_idx);
}

// Round 9
// 335.306 us; speedup vs baseline: 1.5347x; 1.0223x over previous
//
#include <hip/hip_runtime.h>

#define E_DIM  256
#define N_E    16384
#define N_ROWS 8192
#define HW     1024
#define NPART  128          // n-tiles of 128 cols

typedef _Float16 f16x8 __attribute__((ext_vector_type(8)));
typedef float    f32x4 __attribute__((ext_vector_type(4)));

#define ESCALE   1048576.0f          // 2^20 (exact)
#define UNSCALE  1.9073486328125e-6f // 2^-19: acc*2^-19 == 2*dot

// async 16B global->LDS copy: HW writes lds_base + lane*16 (wave-uniform base)
__device__ __forceinline__ void gld_lds16(_Float16* lds, const _Float16* g) {
  __builtin_amdgcn_global_load_lds(
      (__attribute__((address_space(1))) void*)(g),
      (__attribute__((address_space(3))) void*)(lds), 16, 0, 0);
}

// ---------- fused prep ----------
// [0,2048)    e-limbs + e-norm: thread = 8-elem unit; row = 32 lanes -> shfl tree norm
//             (en order-free: en ~3e-7 << ulp(zn) ~3e-5; see round-9 analysis)
// [2048,2304) z-limbs : thread = (row n, kc); lanes hw-minor (coalesced both ways)
// [2304,2816) z-norm  : 16 threads/row, numpy-exact chains + LDS tree (verified R8)
#define EB_LIMB 2048
#define ZB_LIMB 256
#define ZB_NORM 512
__global__ __launch_bounds__(256) void k_prep(const float* __restrict__ z,
                                              const float* __restrict__ E,
                                              _Float16* __restrict__ Ah,
                                              _Float16* __restrict__ Al,
                                              _Float16* __restrict__ Bh,
                                              _Float16* __restrict__ Bl,
                                              float* __restrict__ eNorm,
                                              float* __restrict__ zNorm,
                                              float* __restrict__ out_loss) {
#pragma clang fp contract(off)
  __shared__ float sN[16][16];
  const int bi = blockIdx.x, t = threadIdx.x;

  if (bi < EB_LIMB) {
    // ---- e-limbs + e-norm: gid = k*32 + m ----
    if (bi == 0 && t == 0) out_loss[0] = 0.f;
    int gid = bi * 256 + t;
    int k = gid >> 5, m = gid & 31;
    int kc = m >> 2, q = m & 3;
    const int perm = (k >> 1) & 3;
    float4 v0 = *(const float4*)&E[(size_t)k * E_DIM + m * 8];
    float4 v1 = *(const float4*)&E[(size_t)k * E_DIM + m * 8 + 4];
    float v[8] = {v0.x, v0.y, v0.z, v0.w, v1.x, v1.y, v1.z, v1.w};
    f16x8 hh, ll;
    float r = 0.f;
#pragma unroll
    for (int j = 0; j < 8; ++j) {
      r = r + v[j] * v[j];
      float s = v[j] * ESCALE;
      _Float16 hi = (_Float16)s;
      hh[j] = hi;
      ll[j] = (_Float16)(s - (float)hi);
    }
    size_t dst = (size_t)kc * (N_E * 32) + (size_t)k * 32 + (size_t)(q ^ perm) * 8;
    *(f16x8*)&Bh[dst] = hh;
    *(f16x8*)&Bl[dst] = ll;
    // any-order 32-lane tree (row = 32 consecutive lanes)
    r = r + __shfl_xor(r, 1, 64);
    r = r + __shfl_xor(r, 2, 64);
    r = r + __shfl_xor(r, 4, 64);
    r = r + __shfl_xor(r, 8, 64);
    r = r + __shfl_xor(r, 16, 64);
    if (m == 0) eNorm[k] = r;
  } else if (bi < EB_LIMB + ZB_LIMB) {
    // ---- z-limbs: block = 64 rows x 4 kc; lanes hw-minor (verbatim R8) ----
    int bi2 = bi - EB_LIMB;
    int n0 = (bi2 & 127) * 64;
    int kc = (bi2 >> 7) * 4 + (t >> 6);
    int n = n0 + (t & 63);
    int b = n >> 10, hw = n & 1023;
    const int perm = (n >> 1) & 3;
    const float* zb = z + ((size_t)b * E_DIM + kc * 32) * HW + hw;
#pragma unroll
    for (int q = 0; q < 4; ++q) {
      f16x8 hh, ll;
#pragma unroll
      for (int j = 0; j < 8; ++j) {
        float v = zb[(size_t)(q * 8 + j) * HW];
        _Float16 hi = (_Float16)v;
        hh[j] = hi;
        ll[j] = (_Float16)(v - (float)hi);
      }
      size_t dst = (size_t)kc * (N_ROWS * 32) + (size_t)n * 32 + (size_t)(q ^ perm) * 8;
      *(f16x8*)&Ah[dst] = hh;
      *(f16x8*)&Al[dst] = ll;
    }
  } else {
    // ---- z-norm: numpy-exact chains + LDS tree (verbatim R8) ----
    int bi2 = bi - (EB_LIMB + ZB_LIMB);
    int n0 = bi2 * 16;
    int nl = t & 15, c16 = t >> 4;
    int h = c16 >> 3, j = c16 & 7;
    int n = n0 + nl;
    int b = n >> 10, hw = n & 1023;
    const float* p = z + ((size_t)b * E_DIM + h * 128 + j) * HW + hw;
    float r = 0.f;
#pragma unroll
    for (int i = 0; i < 16; ++i) { float v = p[(size_t)i * 8 * HW]; r = r + v * v; }
    sN[nl][c16] = r;
    __syncthreads();
    if (t < 16) {
      const float* q = sN[t];
      float h0 = ((q[0] + q[1]) + (q[2] + q[3])) + ((q[4] + q[5]) + (q[6] + q[7]));
      float h1 = ((q[8] + q[9]) + (q[10] + q[11])) + ((q[12] + q[13]) + (q[14] + q[15]));
      zNorm[n0 + t] = h0 + h1;
    }
  }
}

// ---------- main: 3-pass fp16-limb MFMA GEMM, block 128x128, wave 64x64 ----------
// Proven config: 248 us, MfmaUtil 37.5%, VGPR 68, 0 conflicts (m97-class plateau)
__global__ __launch_bounds__(256, 3) void k_scores_mfma(
    const _Float16* __restrict__ Ah, const _Float16* __restrict__ Al,
    const _Float16* __restrict__ Bh, const _Float16* __restrict__ Bl,
    const float* __restrict__ eNorm, const float* __restrict__ zNorm,
    float* __restrict__ pVal, int* __restrict__ pIdx) {
#pragma clang fp contract(off)
  __shared__ alignas(16) _Float16 As[2][128][32];  // 16 KB: limb, row, swizzled 32 f16
  __shared__ alignas(16) _Float16 Bs[2][128][32];  // 16 KB

  const int mt = blockIdx.x, nt = blockIdx.y;
  const int m0 = mt * 128, n0 = nt * 128;

  const int t = threadIdx.x;
  const int lane = t & 63, w = t >> 6;
  const int tx = lane & 15, quad = lane >> 4;
  const int wm = (w >> 1) * 64, wn = (w & 1) * 64;
  const int swz = (quad ^ ((tx >> 1) & 3)) * 8;    // physical f16 offset of logical block

  const _Float16* gseg;
  size_t plane;
  _Float16* lseg;
  if (w == 0)      { gseg = Ah + (size_t)m0 * 32; plane = (size_t)N_ROWS * 32; lseg = &As[0][0][0]; }
  else if (w == 1) { gseg = Al + (size_t)m0 * 32; plane = (size_t)N_ROWS * 32; lseg = &As[1][0][0]; }
  else if (w == 2) { gseg = Bh + (size_t)n0 * 32; plane = (size_t)N_E * 32;    lseg = &Bs[0][0][0]; }
  else             { gseg = Bl + (size_t)n0 * 32; plane = (size_t)N_E * 32;    lseg = &Bs[1][0][0]; }

  f32x4 acc[4][4];
#pragma unroll
  for (int i = 0; i < 4; ++i)
#pragma unroll
    for (int j = 0; j < 4; ++j) acc[i][j] = (f32x4){0.f, 0.f, 0.f, 0.f};

  for (int kc = 0; kc < 8; ++kc) {
    __syncthreads();                       // previous iteration's frag reads done
    const _Float16* g = gseg + (size_t)kc * plane + lane * 8;
#pragma unroll
    for (int c = 0; c < 8; ++c)
      gld_lds16(lseg + c * 512, g + c * 512);   // 8 x 1KB async copies per wave
    __syncthreads();                       // vmcnt(0) drained before barrier -> data visible

    f16x8 bh[4], bl[4];
#pragma unroll
    for (int j = 0; j < 4; ++j) {
      bh[j] = *(const f16x8*)&Bs[0][wn + j * 16 + tx][swz];
      bl[j] = *(const f16x8*)&Bs[1][wn + j * 16 + tx][swz];
    }
#pragma unroll
    for (int i = 0; i < 4; ++i) {
      f16x8 ah = *(const f16x8*)&As[0][wm + i * 16 + tx][swz];
      f16x8 al = *(const f16x8*)&As[1][wm + i * 16 + tx][swz];
#pragma unroll
      for (int j = 0; j < 4; ++j) {
        acc[i][j] = __builtin_amdgcn_mfma_f32_16x16x32_f16(ah, bh[j], acc[i][j], 0, 0, 0);
        acc[i][j] = __builtin_amdgcn_mfma_f32_16x16x32_f16(ah, bl[j], acc[i][j], 0, 0, 0);
        acc[i][j] = __builtin_amdgcn_mfma_f32_16x16x32_f16(al, bh[j], acc[i][j], 0, 0, 0);
      }
    }
  }

  // ---- epilogue: score + argmin (first-index tie-break) ----
  __syncthreads();
  float* sF  = (float*)&As[0][0][0];
  float* zNl = sF;                 // [128]
  float* eNl = sF + 128;           // [128]
  float* sV  = sF + 256;           // [2][128]
  int*   sI  = (int*)(sF + 512);   // [2][128]
  if (t < 128) zNl[t] = zNorm[m0 + t];
  else         eNl[t - 128] = eNorm[n0 + t - 128];
  __syncthreads();

#pragma unroll
  for (int i = 0; i < 4; ++i) {
#pragma unroll
    for (int r = 0; r < 4; ++r) {
      const int rloc = wm + i * 16 + quad * 4 + r;
      const float zn = zNl[rloc];
      float bv = 3.4e38f;
      int bc = 0x7fffffff;
#pragma unroll
      for (int j = 0; j < 4; ++j) {
        const int col = wn + j * 16 + tx;
        float s = (zn + eNl[col]) - acc[i][j][r] * UNSCALE;
        if (s < bv) { bv = s; bc = n0 + col; }   // j ascending: strict < keeps lowest col
      }
#pragma unroll
      for (int off = 1; off < 16; off <<= 1) {
        float ov = __shfl_xor(bv, off, 64);
        int oc = __shfl_xor(bc, off, 64);
        if (ov < bv || (ov == bv && oc < bc)) { bv = ov; bc = oc; }
      }
      if (tx == 0) { sV[(w & 1) * 128 + rloc] = bv; sI[(w & 1) * 128 + rloc] = bc; }
    }
  }
  __syncthreads();
  if (t < 128) {
    float v0 = sV[t], v1 = sV[128 + t];
    int i0 = sI[t], i1 = sI[128 + t];
    int take1 = (v1 < v0) || (v1 == v0 && i1 < i0);
    pVal[(size_t)nt * N_ROWS + m0 + t] = take1 ? v1 : v0;
    pIdx[(size_t)nt * N_ROWS + m0 + t] = take1 ? i1 : i0;
  }
}

// ---------- fused post: argmin over 128 partials (2-stage) + gather + loss ----------
// grid 512 blocks, block = 16 rows x 16 scanners; then 16 rows x 16 channel-chunks.
// Lexicographic pair-min is associative+commutative -> any reduction shape exact.
__global__ __launch_bounds__(256) void k_post(const float* __restrict__ pVal,
                                              const int* __restrict__ pIdx,
                                              const float* __restrict__ z,
                                              const float* __restrict__ E,
                                              float* __restrict__ out,
                                              float* __restrict__ out_loss,
                                              float* __restrict__ out_idx) {
  __shared__ float sV[16][16];
  __shared__ int   sI[16][16];
  __shared__ int   fI[16];
  const int t = threadIdx.x;
  const int r = t & 15, s = t >> 4;
  const int n0 = blockIdx.x * 16;
  const int n = n0 + r;

  float mv = 3.4e38f;
  int mi = 0x7fffffff;
#pragma unroll
  for (int i = 0; i < 8; ++i) {
    int s2 = s * 8 + i;
    float v = pVal[(size_t)s2 * N_ROWS + n];
    int id = pIdx[(size_t)s2 * N_ROWS + n];
    if (v < mv || (v == mv && id < mi)) { mv = v; mi = id; }
  }
  sV[s][r] = mv;
  sI[s][r] = mi;
  __syncthreads();
  if (t < 16) {
    float bv = sV[0][t];
    int bc = sI[0][t];
#pragma unroll
    for (int s3 = 1; s3 < 16; ++s3) {
      float v = sV[s3][t];
      int id = sI[s3][t];
      if (v < bv || (v == bv && id < bc)) { bv = v; bc = id; }
    }
    fI[t] = bc;
    out_idx[n0 + t] = (float)bc;
  }
  __syncthreads();

  // gather: thread = (row r, channel chunk s of 16)
  const int idx = fI[r];
  const int b = n >> 10, hw = n & 1023;
  const float4* erow4 = (const float4*)(E + (size_t)idx * E_DIM + s * 16);
  const float* zrow = z + ((size_t)b * E_DIM + s * 16) * HW + hw;
  float* orow = out + ((size_t)b * E_DIM + s * 16) * HW + hw;
  float acc = 0.f;
#pragma unroll
  for (int c4 = 0; c4 < 4; ++c4) {
    float4 e4 = erow4[c4];
    float ev[4] = {e4.x, e4.y, e4.z, e4.w};
#pragma unroll
    for (int j2 = 0; j2 < 4; ++j2) {
      int c = c4 * 4 + j2;
      float zv = zrow[(size_t)c * HW];
      orow[(size_t)c * HW] = ev[j2];
      float d = ev[j2] - zv;
      acc = fmaf(d, d, acc);
    }
  }
  for (int off = 32; off > 0; off >>= 1) acc += __shfl_down(acc, off, 64);
  __shared__ float wsum[4];
  if ((t & 63) == 0) wsum[t >> 6] = acc;
  __syncthreads();
  if (t == 0)
    atomicAdd(out_loss, ((wsum[0] + wsum[1]) + (wsum[2] + wsum[3])) * (1.25f / 2097152.f));
}

extern "C" void kernel_launch(void* const* d_in, const int* in_sizes, int n_in,
                              void* d_out, int out_size, void* d_ws, size_t ws_size,
                              hipStream_t stream) {
  const float* z = (const float*)d_in[0];
  const float* E = (const float*)d_in[1];
  float* out = (float*)d_out;
  float* out_loss = out + 2097152;  // after z_q (8*256*32*32)
  float* out_idx = out + 2097153;

  // workspace (~32 MB): Ah|Al f16[8][8192][32], Bh|Bl f16[8][16384][32],
  //                     eNorm, zNorm, pVal[128][8192], pIdx[128][8192]
  _Float16* Ah = (_Float16*)d_ws;
  _Float16* Al = Ah + (size_t)N_ROWS * E_DIM;
  _Float16* Bh = Al + (size_t)N_ROWS * E_DIM;
  _Float16* Bl = Bh + (size_t)N_E * E_DIM;
  float* eNorm = (float*)(Bl + (size_t)N_E * E_DIM);
  float* zNorm = eNorm + N_E;
  float* pVal = zNorm + N_ROWS;
  int* pIdx = (int*)(pVal + (size_t)NPART * N_ROWS);

  k_prep<<<EB_LIMB + ZB_LIMB + ZB_NORM, 256, 0, stream>>>(
      z, E, Ah, Al, Bh, Bl, eNorm, zNorm, out_loss);
  k_scores_mfma<<<dim3(N_ROWS / 128, N_E / 128), 256, 0, stream>>>(
      Ah, Al, Bh, Bl, eNorm, zNorm, pVal, pIdx);
  k_post<<<N_ROWS / 16, 256, 0, stream>>>(pVal, pIdx, z, E, out, out_loss, out_idx);
}

// Round 10
// 327.819 us; speedup vs baseline: 1.5697x; 1.0228x over previous
//
#include <hip/hip_runtime.h>

#define E_DIM  256
#define N_E    16384
#define N_ROWS 8192
#define HW     1024
#define NPART  128          // n-tiles of 128 cols

typedef _Float16 f16x8 __attribute__((ext_vector_type(8)));
typedef float    f32x4 __attribute__((ext_vector_type(4)));

#define ESCALE   1048576.0f          // 2^20 (exact)
#define UNSCALE  1.9073486328125e-6f // 2^-19: acc*2^-19 == 2*dot

// async 16B global->LDS copy: HW writes lds_base + lane*16 (wave-uniform base)
__device__ __forceinline__ void gld_lds16(_Float16* lds, const _Float16* g) {
  __builtin_amdgcn_global_load_lds(
      (__attribute__((address_space(1))) void*)(g),
      (__attribute__((address_space(3))) void*)(lds), 16, 0, 0);
}

// ---------- fused prep ----------
// [0,2048)    e-limbs + e-norm: thread = 8-elem unit; row = 32 lanes -> shfl tree norm
//             (en order-free: en ~1e-6 << ulp(zn) ~3e-5; flips ~0 quantized scores)
// [2048,2304) z-tile: 32 rows x 256 ch staged in LDS once; limbs (phase L) and
//             numpy-exact norm chains (phase N) both read the tile. z read 1x.
#define EB_LIMB 2048
#define ZB_Z    256
__global__ __launch_bounds__(256) void k_prep(const float* __restrict__ z,
                                              const float* __restrict__ E,
                                              _Float16* __restrict__ Ah,
                                              _Float16* __restrict__ Al,
                                              _Float16* __restrict__ Bh,
                                              _Float16* __restrict__ Bl,
                                              float* __restrict__ eNorm,
                                              float* __restrict__ zNorm,
                                              float* __restrict__ out_loss) {
#pragma clang fp contract(off)
  __shared__ float sLZ[256][32];   // 32 KB z tile [channel][row]
  __shared__ float sN2[16][32];    // 2 KB chain partials [c16][row]
  const int bi = blockIdx.x, t = threadIdx.x;

  if (bi < EB_LIMB) {
    // ---- e-limbs + e-norm: gid = k*32 + m (verbatim R9, passed) ----
    if (bi == 0 && t == 0) out_loss[0] = 0.f;
    int gid = bi * 256 + t;
    int k = gid >> 5, m = gid & 31;
    int kc = m >> 2, q = m & 3;
    const int perm = (k >> 1) & 3;
    float4 v0 = *(const float4*)&E[(size_t)k * E_DIM + m * 8];
    float4 v1 = *(const float4*)&E[(size_t)k * E_DIM + m * 8 + 4];
    float v[8] = {v0.x, v0.y, v0.z, v0.w, v1.x, v1.y, v1.z, v1.w};
    f16x8 hh, ll;
    float r = 0.f;
#pragma unroll
    for (int j = 0; j < 8; ++j) {
      r = r + v[j] * v[j];
      float s = v[j] * ESCALE;
      _Float16 hi = (_Float16)s;
      hh[j] = hi;
      ll[j] = (_Float16)(s - (float)hi);
    }
    size_t dst = (size_t)kc * (N_E * 32) + (size_t)k * 32 + (size_t)(q ^ perm) * 8;
    *(f16x8*)&Bh[dst] = hh;
    *(f16x8*)&Bl[dst] = ll;
    r = r + __shfl_xor(r, 1, 64);
    r = r + __shfl_xor(r, 2, 64);
    r = r + __shfl_xor(r, 4, 64);
    r = r + __shfl_xor(r, 8, 64);
    r = r + __shfl_xor(r, 16, 64);
    if (m == 0) eNorm[k] = r;
  } else {
    // ---- z section: 32-row tile ----
    const int bz = bi - EB_LIMB;
    const int n0 = bz * 32;
    const int b = n0 >> 10, hw0 = n0 & 1023;   // 32-row tile stays within one b

    // stage: 8 channels x 32 rows per iteration, 128 B segments
    {
      const int nl = t & 31, cs = t >> 5;
      const float* zb = z + (size_t)b * E_DIM * HW + hw0 + nl;
#pragma unroll 4
      for (int it = 0; it < 32; ++it) {
        int c = it * 8 + cs;
        sLZ[c][nl] = zb[(size_t)c * HW];
      }
    }
    __syncthreads();

    // phase L: limbs. thread = (row nl, segment seg of 32 channels)
    {
      const int nl = t & 31, seg = t >> 5;     // seg = kc
      const int n = n0 + nl;
      const int perm = (n >> 1) & 3;
#pragma unroll
      for (int u = 0; u < 4; ++u) {            // u = q
        const int c0 = seg * 32 + u * 8;
        f16x8 hh, ll;
#pragma unroll
        for (int j = 0; j < 8; ++j) {
          float v = sLZ[c0 + j][nl];
          _Float16 hi = (_Float16)v;
          hh[j] = hi;
          ll[j] = (_Float16)(v - (float)hi);
        }
        size_t dst = (size_t)seg * (N_ROWS * 32) + (size_t)n * 32 + (size_t)(u ^ perm) * 8;
        *(f16x8*)&Ah[dst] = hh;
        *(f16x8*)&Al[dst] = ll;
      }
    }

    // phase N: numpy-exact chains, task = (row, h, j); identical op sequence to R8/R9
#pragma unroll
    for (int it = 0; it < 2; ++it) {
      int task = it * 256 + t;
      int nl = task & 31, c16 = task >> 5;     // c16 = h*8 + j
      int h = c16 >> 3, j = c16 & 7;
      float r = 0.f;
#pragma unroll
      for (int i = 0; i < 16; ++i) {
        float v = sLZ[h * 128 + i * 8 + j][nl];
        r = r + v * v;
      }
      sN2[c16][nl] = r;
    }
    __syncthreads();
    if (t < 32) {
      float q[16];
#pragma unroll
      for (int c16 = 0; c16 < 16; ++c16) q[c16] = sN2[c16][t];
      float h0 = ((q[0] + q[1]) + (q[2] + q[3])) + ((q[4] + q[5]) + (q[6] + q[7]));
      float h1 = ((q[8] + q[9]) + (q[10] + q[11])) + ((q[12] + q[13]) + (q[14] + q[15]));
      zNorm[n0 + t] = h0 + h1;
    }
  }
}

// ---------- main: 3-pass fp16-limb MFMA GEMM, block 128x128, wave 64x64 ----------
// Proven config: 244 us, MfmaUtil 37.5%, VGPR 68, 0 conflicts (m97-class plateau)
__global__ __launch_bounds__(256, 3) void k_scores_mfma(
    const _Float16* __restrict__ Ah, const _Float16* __restrict__ Al,
    const _Float16* __restrict__ Bh, const _Float16* __restrict__ Bl,
    const float* __restrict__ eNorm, const float* __restrict__ zNorm,
    float* __restrict__ pVal, int* __restrict__ pIdx) {
#pragma clang fp contract(off)
  __shared__ alignas(16) _Float16 As[2][128][32];  // 16 KB: limb, row, swizzled 32 f16
  __shared__ alignas(16) _Float16 Bs[2][128][32];  // 16 KB

  const int mt = blockIdx.x, nt = blockIdx.y;
  const int m0 = mt * 128, n0 = nt * 128;

  const int t = threadIdx.x;
  const int lane = t & 63, w = t >> 6;
  const int tx = lane & 15, quad = lane >> 4;
  const int wm = (w >> 1) * 64, wn = (w & 1) * 64;
  const int swz = (quad ^ ((tx >> 1) & 3)) * 8;    // physical f16 offset of logical block

  const _Float16* gseg;
  size_t plane;
  _Float16* lseg;
  if (w == 0)      { gseg = Ah + (size_t)m0 * 32; plane = (size_t)N_ROWS * 32; lseg = &As[0][0][0]; }
  else if (w == 1) { gseg = Al + (size_t)m0 * 32; plane = (size_t)N_ROWS * 32; lseg = &As[1][0][0]; }
  else if (w == 2) { gseg = Bh + (size_t)n0 * 32; plane = (size_t)N_E * 32;    lseg = &Bs[0][0][0]; }
  else             { gseg = Bl + (size_t)n0 * 32; plane = (size_t)N_E * 32;    lseg = &Bs[1][0][0]; }

  f32x4 acc[4][4];
#pragma unroll
  for (int i = 0; i < 4; ++i)
#pragma unroll
    for (int j = 0; j < 4; ++j) acc[i][j] = (f32x4){0.f, 0.f, 0.f, 0.f};

  for (int kc = 0; kc < 8; ++kc) {
    __syncthreads();                       // previous iteration's frag reads done
    const _Float16* g = gseg + (size_t)kc * plane + lane * 8;
#pragma unroll
    for (int c = 0; c < 8; ++c)
      gld_lds16(lseg + c * 512, g + c * 512);   // 8 x 1KB async copies per wave
    __syncthreads();                       // vmcnt(0) drained before barrier -> data visible

    f16x8 bh[4], bl[4];
#pragma unroll
    for (int j = 0; j < 4; ++j) {
      bh[j] = *(const f16x8*)&Bs[0][wn + j * 16 + tx][swz];
      bl[j] = *(const f16x8*)&Bs[1][wn + j * 16 + tx][swz];
    }
#pragma unroll
    for (int i = 0; i < 4; ++i) {
      f16x8 ah = *(const f16x8*)&As[0][wm + i * 16 + tx][swz];
      f16x8 al = *(const f16x8*)&As[1][wm + i * 16 + tx][swz];
#pragma unroll
      for (int j = 0; j < 4; ++j) {
        acc[i][j] = __builtin_amdgcn_mfma_f32_16x16x32_f16(ah, bh[j], acc[i][j], 0, 0, 0);
        acc[i][j] = __builtin_amdgcn_mfma_f32_16x16x32_f16(ah, bl[j], acc[i][j], 0, 0, 0);
        acc[i][j] = __builtin_amdgcn_mfma_f32_16x16x32_f16(al, bh[j], acc[i][j], 0, 0, 0);
      }
    }
  }

  // ---- epilogue: score + argmin (first-index tie-break) ----
  __syncthreads();
  float* sF  = (float*)&As[0][0][0];
  float* zNl = sF;                 // [128]
  float* eNl = sF + 128;           // [128]
  float* sV  = sF + 256;           // [2][128]
  int*   sI  = (int*)(sF + 512);   // [2][128]
  if (t < 128) zNl[t] = zNorm[m0 + t];
  else         eNl[t - 128] = eNorm[n0 + t - 128];
  __syncthreads();

#pragma unroll
  for (int i = 0; i < 4; ++i) {
#pragma unroll
    for (int r = 0; r < 4; ++r) {
      const int rloc = wm + i * 16 + quad * 4 + r;
      const float zn = zNl[rloc];
      float bv = 3.4e38f;
      int bc = 0x7fffffff;
#pragma unroll
      for (int j = 0; j < 4; ++j) {
        const int col = wn + j * 16 + tx;
        float s = (zn + eNl[col]) - acc[i][j][r] * UNSCALE;
        if (s < bv) { bv = s; bc = n0 + col; }   // j ascending: strict < keeps lowest col
      }
#pragma unroll
      for (int off = 1; off < 16; off <<= 1) {
        float ov = __shfl_xor(bv, off, 64);
        int oc = __shfl_xor(bc, off, 64);
        if (ov < bv || (ov == bv && oc < bc)) { bv = ov; bc = oc; }
      }
      if (tx == 0) { sV[(w & 1) * 128 + rloc] = bv; sI[(w & 1) * 128 + rloc] = bc; }
    }
  }
  __syncthreads();
  if (t < 128) {
    float v0 = sV[t], v1 = sV[128 + t];
    int i0 = sI[t], i1 = sI[128 + t];
    int take1 = (v1 < v0) || (v1 == v0 && i1 < i0);
    pVal[(size_t)nt * N_ROWS + m0 + t] = take1 ? v1 : v0;
    pIdx[(size_t)nt * N_ROWS + m0 + t] = take1 ? i1 : i0;
  }
}

// ---------- fused post: argmin over 128 partials (2-stage) + gather + loss ----------
// Verbatim R9 (passed). Lexicographic pair-min associative -> exact.
__global__ __launch_bounds__(256) void k_post(const float* __restrict__ pVal,
                                              const int* __restrict__ pIdx,
                                              const float* __restrict__ z,
                                              const float* __restrict__ E,
                                              float* __restrict__ out,
                                              float* __restrict__ out_loss,
                                              float* __restrict__ out_idx) {
  __shared__ float sV[16][16];
  __shared__ int   sI[16][16];
  __shared__ int   fI[16];
  const int t = threadIdx.x;
  const int r = t & 15, s = t >> 4;
  const int n0 = blockIdx.x * 16;
  const int n = n0 + r;

  float mv = 3.4e38f;
  int mi = 0x7fffffff;
#pragma unroll
  for (int i = 0; i < 8; ++i) {
    int s2 = s * 8 + i;
    float v = pVal[(size_t)s2 * N_ROWS + n];
    int id = pIdx[(size_t)s2 * N_ROWS + n];
    if (v < mv || (v == mv && id < mi)) { mv = v; mi = id; }
  }
  sV[s][r] = mv;
  sI[s][r] = mi;
  __syncthreads();
  if (t < 16) {
    float bv = sV[0][t];
    int bc = sI[0][t];
#pragma unroll
    for (int s3 = 1; s3 < 16; ++s3) {
      float v = sV[s3][t];
      int id = sI[s3][t];
      if (v < bv || (v == bv && id < bc)) { bv = v; bc = id; }
    }
    fI[t] = bc;
    out_idx[n0 + t] = (float)bc;
  }
  __syncthreads();

  const int idx = fI[r];
  const int b = n >> 10, hw = n & 1023;
  const float4* erow4 = (const float4*)(E + (size_t)idx * E_DIM + s * 16);
  const float* zrow = z + ((size_t)b * E_DIM + s * 16) * HW + hw;
  float* orow = out + ((size_t)b * E_DIM + s * 16) * HW + hw;
  float acc = 0.f;
#pragma unroll
  for (int c4 = 0; c4 < 4; ++c4) {
    float4 e4 = erow4[c4];
    float ev[4] = {e4.x, e4.y, e4.z, e4.w};
#pragma unroll
    for (int j2 = 0; j2 < 4; ++j2) {
      int c = c4 * 4 + j2;
      float zv = zrow[(size_t)c * HW];
      orow[(size_t)c * HW] = ev[j2];
      float d = ev[j2] - zv;
      acc = fmaf(d, d, acc);
    }
  }
  for (int off = 32; off > 0; off >>= 1) acc += __shfl_down(acc, off, 64);
  __shared__ float wsum[4];
  if ((t & 63) == 0) wsum[t >> 6] = acc;
  __syncthreads();
  if (t == 0)
    atomicAdd(out_loss, ((wsum[0] + wsum[1]) + (wsum[2] + wsum[3])) * (1.25f / 2097152.f));
}

extern "C" void kernel_launch(void* const* d_in, const int* in_sizes, int n_in,
                              void* d_out, int out_size, void* d_ws, size_t ws_size,
                              hipStream_t stream) {
  const float* z = (const float*)d_in[0];
  const float* E = (const float*)d_in[1];
  float* out = (float*)d_out;
  float* out_loss = out + 2097152;  // after z_q (8*256*32*32)
  float* out_idx = out + 2097153;

  // workspace (~32 MB): Ah|Al f16[8][8192][32], Bh|Bl f16[8][16384][32],
  //                     eNorm, zNorm, pVal[128][8192], pIdx[128][8192]
  _Float16* Ah = (_Float16*)d_ws;
  _Float16* Al = Ah + (size_t)N_ROWS * E_DIM;
  _Float16* Bh = Al + (size_t)N_ROWS * E_DIM;
  _Float16* Bl = Bh + (size_t)N_E * E_DIM;
  float* eNorm = (float*)(Bl + (size_t)N_E * E_DIM);
  float* zNorm = eNorm + N_E;
  float* pVal = zNorm + N_ROWS;
  int* pIdx = (int*)(pVal + (size_t)NPART * N_ROWS);

  k_prep<<<EB_LIMB + ZB_Z, 256, 0, stream>>>(
      z, E, Ah, Al, Bh, Bl, eNorm, zNorm, out_loss);
  k_scores_mfma<<<dim3(N_ROWS / 128, N_E / 128), 256, 0, stream>>>(
      Ah, Al, Bh, Bl, eNorm, zNorm, pVal, pIdx);
  k_post<<<N_ROWS / 16, 256, 0, stream>>>(pVal, pIdx, z, E, out, out_loss, out_idx);
}

// Round 11
// 303.949 us; speedup vs baseline: 1.6930x; 1.0785x over previous
//
#include <hip/hip_runtime.h>

#define E_DIM  256
#define N_E    16384
#define N_ROWS 8192
#define HW     1024
#define NPART  128          // n-tiles of 128 cols

typedef _Float16 f16x8 __attribute__((ext_vector_type(8)));
typedef float    f32x4 __attribute__((ext_vector_type(4)));

#define ESCALE   1048576.0f          // 2^20 (exact)
#define UNSCALE  1.9073486328125e-6f // 2^-19: acc*2^-19 == 2*dot

// async 16B global->LDS copy: HW writes lds_base + lane*16 (wave-uniform base)
__device__ __forceinline__ void gld_lds16(_Float16* lds, const _Float16* g) {
  __builtin_amdgcn_global_load_lds(
      (__attribute__((address_space(1))) void*)(g),
      (__attribute__((address_space(3))) void*)(lds), 16, 0, 0);
}

// ---------- fused prep ----------
// [0,256)    z-tile: 32 rows x 256 ch staged in LDS once; limbs + numpy-exact norms
//            (verbatim R10, passed). Placed first: longest HBM pole.
// [256,768)  E-limbs + e-norm: thread = (kc = t>>5, k = 32*blk + (t&31)).
//            Stores: 32 lanes x 64 B contiguous per kc-plane. E read exactly once.
//            e-norm = order-free partial per (kc,k) + LDS combine (en << ulp(zn)).
#define ZB_Z    256
#define EB_E    512
__global__ __launch_bounds__(256) void k_prep(const float* __restrict__ z,
                                              const float* __restrict__ E,
                                              _Float16* __restrict__ Ah,
                                              _Float16* __restrict__ Al,
                                              _Float16* __restrict__ Bh,
                                              _Float16* __restrict__ Bl,
                                              float* __restrict__ eNorm,
                                              float* __restrict__ zNorm,
                                              float* __restrict__ out_loss) {
#pragma clang fp contract(off)
  const int bi = blockIdx.x, t = threadIdx.x;

  if (bi < ZB_Z) {
    // ---- z section: 32-row tile (verbatim R10) ----
    __shared__ float sLZ[256][32];   // 32 KB z tile [channel][row]
    __shared__ float sN2[16][32];    // chain partials [c16][row]
    const int n0 = bi * 32;
    const int b = n0 >> 10, hw0 = n0 & 1023;

    {
      const int nl = t & 31, cs = t >> 5;
      const float* zb = z + (size_t)b * E_DIM * HW + hw0 + nl;
#pragma unroll 4
      for (int it = 0; it < 32; ++it) {
        int c = it * 8 + cs;
        sLZ[c][nl] = zb[(size_t)c * HW];
      }
    }
    __syncthreads();

    // phase L: limbs. thread = (row nl, segment seg = kc)
    {
      const int nl = t & 31, seg = t >> 5;
      const int n = n0 + nl;
      const int perm = (n >> 1) & 3;
#pragma unroll
      for (int u = 0; u < 4; ++u) {
        const int c0 = seg * 32 + u * 8;
        f16x8 hh, ll;
#pragma unroll
        for (int j = 0; j < 8; ++j) {
          float v = sLZ[c0 + j][nl];
          _Float16 hi = (_Float16)v;
          hh[j] = hi;
          ll[j] = (_Float16)(v - (float)hi);
        }
        size_t dst = (size_t)seg * (N_ROWS * 32) + (size_t)n * 32 + (size_t)(u ^ perm) * 8;
        *(f16x8*)&Ah[dst] = hh;
        *(f16x8*)&Al[dst] = ll;
      }
    }

    // phase N: numpy-exact chains (verbatim R10)
#pragma unroll
    for (int it = 0; it < 2; ++it) {
      int task = it * 256 + t;
      int nl = task & 31, c16 = task >> 5;
      int h = c16 >> 3, j = c16 & 7;
      float r = 0.f;
#pragma unroll
      for (int i = 0; i < 16; ++i) {
        float v = sLZ[h * 128 + i * 8 + j][nl];
        r = r + v * v;
      }
      sN2[c16][nl] = r;
    }
    __syncthreads();
    if (t < 32) {
      float q[16];
#pragma unroll
      for (int c16 = 0; c16 < 16; ++c16) q[c16] = sN2[c16][t];
      float h0 = ((q[0] + q[1]) + (q[2] + q[3])) + ((q[4] + q[5]) + (q[6] + q[7]));
      float h1 = ((q[8] + q[9]) + (q[10] + q[11])) + ((q[12] + q[13]) + (q[14] + q[15]));
      zNorm[n0 + t] = h0 + h1;
    }
  } else {
    // ---- E section ----
    __shared__ float sNP[8][32];
    const int be = bi - ZB_Z;
    if (be == 0 && t == 0) out_loss[0] = 0.f;
    const int kc = t >> 5, rl = t & 31;
    const int k = be * 32 + rl;
    const int perm = (k >> 1) & 3;
    const float* src = E + (size_t)k * E_DIM + kc * 32;

    float4 v4[8];
#pragma unroll
    for (int u2 = 0; u2 < 8; ++u2) v4[u2] = ((const float4*)src)[u2];

    float nsum = 0.f;
    size_t base = (size_t)kc * (N_E * 32) + (size_t)k * 32;
#pragma unroll
    for (int u = 0; u < 4; ++u) {
      float v[8] = {v4[u * 2].x, v4[u * 2].y, v4[u * 2].z, v4[u * 2].w,
                    v4[u * 2 + 1].x, v4[u * 2 + 1].y, v4[u * 2 + 1].z, v4[u * 2 + 1].w};
      f16x8 hh, ll;
#pragma unroll
      for (int j = 0; j < 8; ++j) {
        nsum = nsum + v[j] * v[j];
        float s = v[j] * ESCALE;
        _Float16 hi = (_Float16)s;
        hh[j] = hi;
        ll[j] = (_Float16)(s - (float)hi);
      }
      *(f16x8*)&Bh[base + (size_t)(u ^ perm) * 8] = hh;
      *(f16x8*)&Bl[base + (size_t)(u ^ perm) * 8] = ll;
    }
    sNP[kc][rl] = nsum;
    __syncthreads();
    if (t < 32) {
      float s = 0.f;
#pragma unroll
      for (int kc2 = 0; kc2 < 8; ++kc2) s += sNP[kc2][t];
      eNorm[be * 32 + t] = s;
    }
  }
}

// ---------- main: 3-pass fp16-limb MFMA GEMM, block 128x128, wave 64x64 ----------
// Proven config: ~250 us, MfmaUtil ~37.5%, VGPR 68, 0 conflicts (m97-class plateau)
__global__ __launch_bounds__(256, 3) void k_scores_mfma(
    const _Float16* __restrict__ Ah, const _Float16* __restrict__ Al,
    const _Float16* __restrict__ Bh, const _Float16* __restrict__ Bl,
    const float* __restrict__ eNorm, const float* __restrict__ zNorm,
    float* __restrict__ pVal, int* __restrict__ pIdx) {
#pragma clang fp contract(off)
  __shared__ alignas(16) _Float16 As[2][128][32];  // 16 KB: limb, row, swizzled 32 f16
  __shared__ alignas(16) _Float16 Bs[2][128][32];  // 16 KB

  const int mt = blockIdx.x, nt = blockIdx.y;
  const int m0 = mt * 128, n0 = nt * 128;

  const int t = threadIdx.x;
  const int lane = t & 63, w = t >> 6;
  const int tx = lane & 15, quad = lane >> 4;
  const int wm = (w >> 1) * 64, wn = (w & 1) * 64;
  const int swz = (quad ^ ((tx >> 1) & 3)) * 8;    // physical f16 offset of logical block

  const _Float16* gseg;
  size_t plane;
  _Float16* lseg;
  if (w == 0)      { gseg = Ah + (size_t)m0 * 32; plane = (size_t)N_ROWS * 32; lseg = &As[0][0][0]; }
  else if (w == 1) { gseg = Al + (size_t)m0 * 32; plane = (size_t)N_ROWS * 32; lseg = &As[1][0][0]; }
  else if (w == 2) { gseg = Bh + (size_t)n0 * 32; plane = (size_t)N_E * 32;    lseg = &Bs[0][0][0]; }
  else             { gseg = Bl + (size_t)n0 * 32; plane = (size_t)N_E * 32;    lseg = &Bs[1][0][0]; }

  f32x4 acc[4][4];
#pragma unroll
  for (int i = 0; i < 4; ++i)
#pragma unroll
    for (int j = 0; j < 4; ++j) acc[i][j] = (f32x4){0.f, 0.f, 0.f, 0.f};

  for (int kc = 0; kc < 8; ++kc) {
    __syncthreads();                       // previous iteration's frag reads done
    const _Float16* g = gseg + (size_t)kc * plane + lane * 8;
#pragma unroll
    for (int c = 0; c < 8; ++c)
      gld_lds16(lseg + c * 512, g + c * 512);   // 8 x 1KB async copies per wave
    __syncthreads();                       // vmcnt(0) drained before barrier -> data visible

    f16x8 bh[4], bl[4];
#pragma unroll
    for (int j = 0; j < 4; ++j) {
      bh[j] = *(const f16x8*)&Bs[0][wn + j * 16 + tx][swz];
      bl[j] = *(const f16x8*)&Bs[1][wn + j * 16 + tx][swz];
    }
#pragma unroll
    for (int i = 0; i < 4; ++i) {
      f16x8 ah = *(const f16x8*)&As[0][wm + i * 16 + tx][swz];
      f16x8 al = *(const f16x8*)&As[1][wm + i * 16 + tx][swz];
#pragma unroll
      for (int j = 0; j < 4; ++j) {
        acc[i][j] = __builtin_amdgcn_mfma_f32_16x16x32_f16(ah, bh[j], acc[i][j], 0, 0, 0);
        acc[i][j] = __builtin_amdgcn_mfma_f32_16x16x32_f16(ah, bl[j], acc[i][j], 0, 0, 0);
        acc[i][j] = __builtin_amdgcn_mfma_f32_16x16x32_f16(al, bh[j], acc[i][j], 0, 0, 0);
      }
    }
  }

  // ---- epilogue: score + argmin (first-index tie-break) ----
  __syncthreads();
  float* sF  = (float*)&As[0][0][0];
  float* zNl = sF;                 // [128]
  float* eNl = sF + 128;           // [128]
  float* sV  = sF + 256;           // [2][128]
  int*   sI  = (int*)(sF + 512);   // [2][128]
  if (t < 128) zNl[t] = zNorm[m0 + t];
  else         eNl[t - 128] = eNorm[n0 + t - 128];
  __syncthreads();

#pragma unroll
  for (int i = 0; i < 4; ++i) {
#pragma unroll
    for (int r = 0; r < 4; ++r) {
      const int rloc = wm + i * 16 + quad * 4 + r;
      const float zn = zNl[rloc];
      float bv = 3.4e38f;
      int bc = 0x7fffffff;
#pragma unroll
      for (int j = 0; j < 4; ++j) {
        const int col = wn + j * 16 + tx;
        float s = (zn + eNl[col]) - acc[i][j][r] * UNSCALE;
        if (s < bv) { bv = s; bc = n0 + col; }   // j ascending: strict < keeps lowest col
      }
#pragma unroll
      for (int off = 1; off < 16; off <<= 1) {
        float ov = __shfl_xor(bv, off, 64);
        int oc = __shfl_xor(bc, off, 64);
        if (ov < bv || (ov == bv && oc < bc)) { bv = ov; bc = oc; }
      }
      if (tx == 0) { sV[(w & 1) * 128 + rloc] = bv; sI[(w & 1) * 128 + rloc] = bc; }
    }
  }
  __syncthreads();
  if (t < 128) {
    float v0 = sV[t], v1 = sV[128 + t];
    int i0 = sI[t], i1 = sI[128 + t];
    int take1 = (v1 < v0) || (v1 == v0 && i1 < i0);
    pVal[(size_t)nt * N_ROWS + m0 + t] = take1 ? v1 : v0;
    pIdx[(size_t)nt * N_ROWS + m0 + t] = take1 ? i1 : i0;
  }
}

// ---------- fused post: argmin over 128 partials + gather + loss ----------
// 256 blocks, block = 32 rows x 8 scanners/chunks; 128 B segments everywhere.
// Lexicographic pair-min associative -> exact.
__global__ __launch_bounds__(256) void k_post(const float* __restrict__ pVal,
                                              const int* __restrict__ pIdx,
                                              const float* __restrict__ z,
                                              const float* __restrict__ E,
                                              float* __restrict__ out,
                                              float* __restrict__ out_loss,
                                              float* __restrict__ out_idx) {
  __shared__ float sV[8][32];
  __shared__ int   sI[8][32];
  __shared__ int   fI[32];
  const int t = threadIdx.x;
  const int r = t & 31, s = t >> 5;
  const int n0 = blockIdx.x * 32;
  const int n = n0 + r;

  float mv = 3.4e38f;
  int mi = 0x7fffffff;
#pragma unroll
  for (int i = 0; i < 16; ++i) {
    int s2 = s * 16 + i;
    float v = pVal[(size_t)s2 * N_ROWS + n];
    int id = pIdx[(size_t)s2 * N_ROWS + n];
    if (v < mv || (v == mv && id < mi)) { mv = v; mi = id; }
  }
  sV[s][r] = mv;
  sI[s][r] = mi;
  __syncthreads();
  if (t < 32) {
    float bv = sV[0][t];
    int bc = sI[0][t];
#pragma unroll
    for (int s3 = 1; s3 < 8; ++s3) {
      float v = sV[s3][t];
      int id = sI[s3][t];
      if (v < bv || (v == bv && id < bc)) { bv = v; bc = id; }
    }
    fI[t] = bc;
    out_idx[n0 + t] = (float)bc;
  }
  __syncthreads();

  // gather: thread = (row r, 32-channel chunk s)
  const int idx = fI[r];
  const int b = n >> 10, hw = n & 1023;
  const float4* erow4 = (const float4*)(E + (size_t)idx * E_DIM + s * 32);
  const float* zrow = z + ((size_t)b * E_DIM + s * 32) * HW + hw;
  float* orow = out + ((size_t)b * E_DIM + s * 32) * HW + hw;
  float acc = 0.f;
#pragma unroll
  for (int c4 = 0; c4 < 8; ++c4) {
    float4 e4 = erow4[c4];
    float ev[4] = {e4.x, e4.y, e4.z, e4.w};
#pragma unroll
    for (int j2 = 0; j2 < 4; ++j2) {
      int c = c4 * 4 + j2;
      float zv = zrow[(size_t)c * HW];
      orow[(size_t)c * HW] = ev[j2];
      float d = ev[j2] - zv;
      acc = fmaf(d, d, acc);
    }
  }
  for (int off = 32; off > 0; off >>= 1) acc += __shfl_down(acc, off, 64);
  __shared__ float wsum[4];
  if ((t & 63) == 0) wsum[t >> 6] = acc;
  __syncthreads();
  if (t == 0)
    atomicAdd(out_loss, ((wsum[0] + wsum[1]) + (wsum[2] + wsum[3])) * (1.25f / 2097152.f));
}

extern "C" void kernel_launch(void* const* d_in, const int* in_sizes, int n_in,
                              void* d_out, int out_size, void* d_ws, size_t ws_size,
                              hipStream_t stream) {
  const float* z = (const float*)d_in[0];
  const float* E = (const float*)d_in[1];
  float* out = (float*)d_out;
  float* out_loss = out + 2097152;  // after z_q (8*256*32*32)
  float* out_idx = out + 2097153;

  // workspace (~32 MB): Ah|Al f16[8][8192][32], Bh|Bl f16[8][16384][32],
  //                     eNorm, zNorm, pVal[128][8192], pIdx[128][8192]
  _Float16* Ah = (_Float16*)d_ws;
  _Float16* Al = Ah + (size_t)N_ROWS * E_DIM;
  _Float16* Bh = Al + (size_t)N_ROWS * E_DIM;
  _Float16* Bl = Bh + (size_t)N_E * E_DIM;
  float* eNorm = (float*)(Bl + (size_t)N_E * E_DIM);
  float* zNorm = eNorm + N_E;
  float* pVal = zNorm + N_ROWS;
  int* pIdx = (int*)(pVal + (size_t)NPART * N_ROWS);

  k_prep<<<ZB_Z + EB_E, 256, 0, stream>>>(
      z, E, Ah, Al, Bh, Bl, eNorm, zNorm, out_loss);
  k_scores_mfma<<<dim3(N_ROWS / 128, N_E / 128), 256, 0, stream>>>(
      Ah, Al, Bh, Bl, eNorm, zNorm, pVal, pIdx);
  k_post<<<N_ROWS / 32, 256, 0, stream>>>(pVal, pIdx, z, E, out, out_loss, out_idx);
}

// Round 12
// 296.147 us; speedup vs baseline: 1.7376x; 1.0263x over previous
//
#include <hip/hip_runtime.h>

#define E_DIM  256
#define N_E    16384
#define N_ROWS 8192
#define HW     1024
#define NPART  128          // n-tiles of 128 cols

typedef _Float16 f16x8 __attribute__((ext_vector_type(8)));
typedef float    f32x4 __attribute__((ext_vector_type(4)));

#define ESCALE   1048576.0f          // 2^20 (exact)
#define UNSCALE  1.9073486328125e-6f // 2^-19: acc*2^-19 == 2*dot

// async 16B global->LDS copy: HW writes lds_base + lane*16 (wave-uniform base)
__device__ __forceinline__ void gld_lds16(_Float16* lds, const _Float16* g) {
  __builtin_amdgcn_global_load_lds(
      (__attribute__((address_space(1))) void*)(g),
      (__attribute__((address_space(3))) void*)(lds), 16, 0, 0);
}

// ---------- fused prep (verbatim R11, passed) ----------
#define ZB_Z    256
#define EB_E    512
__global__ __launch_bounds__(256) void k_prep(const float* __restrict__ z,
                                              const float* __restrict__ E,
                                              _Float16* __restrict__ Ah,
                                              _Float16* __restrict__ Al,
                                              _Float16* __restrict__ Bh,
                                              _Float16* __restrict__ Bl,
                                              float* __restrict__ eNorm,
                                              float* __restrict__ zNorm,
                                              float* __restrict__ out_loss) {
#pragma clang fp contract(off)
  const int bi = blockIdx.x, t = threadIdx.x;

  if (bi < ZB_Z) {
    // ---- z section: 32-row tile ----
    __shared__ float sLZ[256][32];   // 32 KB z tile [channel][row]
    __shared__ float sN2[16][32];    // chain partials [c16][row]
    const int n0 = bi * 32;
    const int b = n0 >> 10, hw0 = n0 & 1023;

    {
      const int nl = t & 31, cs = t >> 5;
      const float* zb = z + (size_t)b * E_DIM * HW + hw0 + nl;
#pragma unroll 4
      for (int it = 0; it < 32; ++it) {
        int c = it * 8 + cs;
        sLZ[c][nl] = zb[(size_t)c * HW];
      }
    }
    __syncthreads();

    // phase L: limbs. thread = (row nl, segment seg = kc)
    {
      const int nl = t & 31, seg = t >> 5;
      const int n = n0 + nl;
      const int perm = (n >> 1) & 3;
#pragma unroll
      for (int u = 0; u < 4; ++u) {
        const int c0 = seg * 32 + u * 8;
        f16x8 hh, ll;
#pragma unroll
        for (int j = 0; j < 8; ++j) {
          float v = sLZ[c0 + j][nl];
          _Float16 hi = (_Float16)v;
          hh[j] = hi;
          ll[j] = (_Float16)(v - (float)hi);
        }
        size_t dst = (size_t)seg * (N_ROWS * 32) + (size_t)n * 32 + (size_t)(u ^ perm) * 8;
        *(f16x8*)&Ah[dst] = hh;
        *(f16x8*)&Al[dst] = ll;
      }
    }

    // phase N: numpy-exact chains
#pragma unroll
    for (int it = 0; it < 2; ++it) {
      int task = it * 256 + t;
      int nl = task & 31, c16 = task >> 5;
      int h = c16 >> 3, j = c16 & 7;
      float r = 0.f;
#pragma unroll
      for (int i = 0; i < 16; ++i) {
        float v = sLZ[h * 128 + i * 8 + j][nl];
        r = r + v * v;
      }
      sN2[c16][nl] = r;
    }
    __syncthreads();
    if (t < 32) {
      float q[16];
#pragma unroll
      for (int c16 = 0; c16 < 16; ++c16) q[c16] = sN2[c16][t];
      float h0 = ((q[0] + q[1]) + (q[2] + q[3])) + ((q[4] + q[5]) + (q[6] + q[7]));
      float h1 = ((q[8] + q[9]) + (q[10] + q[11])) + ((q[12] + q[13]) + (q[14] + q[15]));
      zNorm[n0 + t] = h0 + h1;
    }
  } else {
    // ---- E section ----
    __shared__ float sNP[8][32];
    const int be = bi - ZB_Z;
    if (be == 0 && t == 0) out_loss[0] = 0.f;
    const int kc = t >> 5, rl = t & 31;
    const int k = be * 32 + rl;
    const int perm = (k >> 1) & 3;
    const float* src = E + (size_t)k * E_DIM + kc * 32;

    float4 v4[8];
#pragma unroll
    for (int u2 = 0; u2 < 8; ++u2) v4[u2] = ((const float4*)src)[u2];

    float nsum = 0.f;
    size_t base = (size_t)kc * (N_E * 32) + (size_t)k * 32;
#pragma unroll
    for (int u = 0; u < 4; ++u) {
      float v[8] = {v4[u * 2].x, v4[u * 2].y, v4[u * 2].z, v4[u * 2].w,
                    v4[u * 2 + 1].x, v4[u * 2 + 1].y, v4[u * 2 + 1].z, v4[u * 2 + 1].w};
      f16x8 hh, ll;
#pragma unroll
      for (int j = 0; j < 8; ++j) {
        nsum = nsum + v[j] * v[j];
        float s = v[j] * ESCALE;
        _Float16 hi = (_Float16)s;
        hh[j] = hi;
        ll[j] = (_Float16)(s - (float)hi);
      }
      *(f16x8*)&Bh[base + (size_t)(u ^ perm) * 8] = hh;
      *(f16x8*)&Bl[base + (size_t)(u ^ perm) * 8] = ll;
    }
    sNP[kc][rl] = nsum;
    __syncthreads();
    if (t < 32) {
      float s = 0.f;
#pragma unroll
      for (int kc2 = 0; kc2 < 8; ++kc2) s += sNP[kc2][t];
      eNorm[be * 32 + t] = s;
    }
  }
}

// ---------- main: 3-pass fp16-limb MFMA GEMM, block 128x128, wave 64x64 ----------
// R12 experiment: launch_bounds min-waves 3 -> 4 (VGPR cap 128 >= 68; codegen
// should be unchanged). Tests whether residency was compiler-hinted vs HW-capped.
__global__ __launch_bounds__(256, 4) void k_scores_mfma(
    const _Float16* __restrict__ Ah, const _Float16* __restrict__ Al,
    const _Float16* __restrict__ Bh, const _Float16* __restrict__ Bl,
    const float* __restrict__ eNorm, const float* __restrict__ zNorm,
    float* __restrict__ pVal, int* __restrict__ pIdx) {
#pragma clang fp contract(off)
  __shared__ alignas(16) _Float16 As[2][128][32];  // 16 KB: limb, row, swizzled 32 f16
  __shared__ alignas(16) _Float16 Bs[2][128][32];  // 16 KB

  const int mt = blockIdx.x, nt = blockIdx.y;
  const int m0 = mt * 128, n0 = nt * 128;

  const int t = threadIdx.x;
  const int lane = t & 63, w = t >> 6;
  const int tx = lane & 15, quad = lane >> 4;
  const int wm = (w >> 1) * 64, wn = (w & 1) * 64;
  const int swz = (quad ^ ((tx >> 1) & 3)) * 8;    // physical f16 offset of logical block

  const _Float16* gseg;
  size_t plane;
  _Float16* lseg;
  if (w == 0)      { gseg = Ah + (size_t)m0 * 32; plane = (size_t)N_ROWS * 32; lseg = &As[0][0][0]; }
  else if (w == 1) { gseg = Al + (size_t)m0 * 32; plane = (size_t)N_ROWS * 32; lseg = &As[1][0][0]; }
  else if (w == 2) { gseg = Bh + (size_t)n0 * 32; plane = (size_t)N_E * 32;    lseg = &Bs[0][0][0]; }
  else             { gseg = Bl + (size_t)n0 * 32; plane = (size_t)N_E * 32;    lseg = &Bs[1][0][0]; }

  f32x4 acc[4][4];
#pragma unroll
  for (int i = 0; i < 4; ++i)
#pragma unroll
    for (int j = 0; j < 4; ++j) acc[i][j] = (f32x4){0.f, 0.f, 0.f, 0.f};

  for (int kc = 0; kc < 8; ++kc) {
    __syncthreads();                       // previous iteration's frag reads done
    const _Float16* g = gseg + (size_t)kc * plane + lane * 8;
#pragma unroll
    for (int c = 0; c < 8; ++c)
      gld_lds16(lseg + c * 512, g + c * 512);   // 8 x 1KB async copies per wave
    __syncthreads();                       // vmcnt(0) drained before barrier -> data visible

    f16x8 bh[4], bl[4];
#pragma unroll
    for (int j = 0; j < 4; ++j) {
      bh[j] = *(const f16x8*)&Bs[0][wn + j * 16 + tx][swz];
      bl[j] = *(const f16x8*)&Bs[1][wn + j * 16 + tx][swz];
    }
#pragma unroll
    for (int i = 0; i < 4; ++i) {
      f16x8 ah = *(const f16x8*)&As[0][wm + i * 16 + tx][swz];
      f16x8 al = *(const f16x8*)&As[1][wm + i * 16 + tx][swz];
#pragma unroll
      for (int j = 0; j < 4; ++j) {
        acc[i][j] = __builtin_amdgcn_mfma_f32_16x16x32_f16(ah, bh[j], acc[i][j], 0, 0, 0);
        acc[i][j] = __builtin_amdgcn_mfma_f32_16x16x32_f16(ah, bl[j], acc[i][j], 0, 0, 0);
        acc[i][j] = __builtin_amdgcn_mfma_f32_16x16x32_f16(al, bh[j], acc[i][j], 0, 0, 0);
      }
    }
  }

  // ---- epilogue: score + argmin (first-index tie-break) ----
  __syncthreads();
  float* sF  = (float*)&As[0][0][0];
  float* zNl = sF;                 // [128]
  float* eNl = sF + 128;           // [128]
  float* sV  = sF + 256;           // [2][128]
  int*   sI  = (int*)(sF + 512);   // [2][128]
  if (t < 128) zNl[t] = zNorm[m0 + t];
  else         eNl[t - 128] = eNorm[n0 + t - 128];
  __syncthreads();

#pragma unroll
  for (int i = 0; i < 4; ++i) {
#pragma unroll
    for (int r = 0; r < 4; ++r) {
      const int rloc = wm + i * 16 + quad * 4 + r;
      const float zn = zNl[rloc];
      float bv = 3.4e38f;
      int bc = 0x7fffffff;
#pragma unroll
      for (int j = 0; j < 4; ++j) {
        const int col = wn + j * 16 + tx;
        float s = (zn + eNl[col]) - acc[i][j][r] * UNSCALE;
        if (s < bv) { bv = s; bc = n0 + col; }   // j ascending: strict < keeps lowest col
      }
#pragma unroll
      for (int off = 1; off < 16; off <<= 1) {
        float ov = __shfl_xor(bv, off, 64);
        int oc = __shfl_xor(bc, off, 64);
        if (ov < bv || (ov == bv && oc < bc)) { bv = ov; bc = oc; }
      }
      if (tx == 0) { sV[(w & 1) * 128 + rloc] = bv; sI[(w & 1) * 128 + rloc] = bc; }
    }
  }
  __syncthreads();
  if (t < 128) {
    float v0 = sV[t], v1 = sV[128 + t];
    int i0 = sI[t], i1 = sI[128 + t];
    int take1 = (v1 < v0) || (v1 == v0 && i1 < i0);
    pVal[(size_t)nt * N_ROWS + m0 + t] = take1 ? v1 : v0;
    pIdx[(size_t)nt * N_ROWS + m0 + t] = take1 ? i1 : i0;
  }
}

// ---------- fused post (verbatim R11, passed) ----------
__global__ __launch_bounds__(256) void k_post(const float* __restrict__ pVal,
                                              const int* __restrict__ pIdx,
                                              const float* __restrict__ z,
                                              const float* __restrict__ E,
                                              float* __restrict__ out,
                                              float* __restrict__ out_loss,
                                              float* __restrict__ out_idx) {
  __shared__ float sV[8][32];
  __shared__ int   sI[8][32];
  __shared__ int   fI[32];
  const int t = threadIdx.x;
  const int r = t & 31, s = t >> 5;
  const int n0 = blockIdx.x * 32;
  const int n = n0 + r;

  float mv = 3.4e38f;
  int mi = 0x7fffffff;
#pragma unroll
  for (int i = 0; i < 16; ++i) {
    int s2 = s * 16 + i;
    float v = pVal[(size_t)s2 * N_ROWS + n];
    int id = pIdx[(size_t)s2 * N_ROWS + n];
    if (v < mv || (v == mv && id < mi)) { mv = v; mi = id; }
  }
  sV[s][r] = mv;
  sI[s][r] = mi;
  __syncthreads();
  if (t < 32) {
    float bv = sV[0][t];
    int bc = sI[0][t];
#pragma unroll
    for (int s3 = 1; s3 < 8; ++s3) {
      float v = sV[s3][t];
      int id = sI[s3][t];
      if (v < bv || (v == bv && id < bc)) { bv = v; bc = id; }
    }
    fI[t] = bc;
    out_idx[n0 + t] = (float)bc;
  }
  __syncthreads();

  const int idx = fI[r];
  const int b = n >> 10, hw = n & 1023;
  const float4* erow4 = (const float4*)(E + (size_t)idx * E_DIM + s * 32);
  const float* zrow = z + ((size_t)b * E_DIM + s * 32) * HW + hw;
  float* orow = out + ((size_t)b * E_DIM + s * 32) * HW + hw;
  float acc = 0.f;
#pragma unroll
  for (int c4 = 0; c4 < 8; ++c4) {
    float4 e4 = erow4[c4];
    float ev[4] = {e4.x, e4.y, e4.z, e4.w};
#pragma unroll
    for (int j2 = 0; j2 < 4; ++j2) {
      int c = c4 * 4 + j2;
      float zv = zrow[(size_t)c * HW];
      orow[(size_t)c * HW] = ev[j2];
      float d = ev[j2] - zv;
      acc = fmaf(d, d, acc);
    }
  }
  for (int off = 32; off > 0; off >>= 1) acc += __shfl_down(acc, off, 64);
  __shared__ float wsum[4];
  if ((t & 63) == 0) wsum[t >> 6] = acc;
  __syncthreads();
  if (t == 0)
    atomicAdd(out_loss, ((wsum[0] + wsum[1]) + (wsum[2] + wsum[3])) * (1.25f / 2097152.f));
}

extern "C" void kernel_launch(void* const* d_in, const int* in_sizes, int n_in,
                              void* d_out, int out_size, void* d_ws, size_t ws_size,
                              hipStream_t stream) {
  const float* z = (const float*)d_in[0];
  const float* E = (const float*)d_in[1];
  float* out = (float*)d_out;
  float* out_loss = out + 2097152;  // after z_q (8*256*32*32)
  float* out_idx = out + 2097153;

  // workspace (~32 MB): Ah|Al f16[8][8192][32], Bh|Bl f16[8][16384][32],
  //                     eNorm, zNorm, pVal[128][8192], pIdx[128][8192]
  _Float16* Ah = (_Float16*)d_ws;
  _Float16* Al = Ah + (size_t)N_ROWS * E_DIM;
  _Float16* Bh = Al + (size_t)N_ROWS * E_DIM;
  _Float16* Bl = Bh + (size_t)N_E * E_DIM;
  float* eNorm = (float*)(Bl + (size_t)N_E * E_DIM);
  float* zNorm = eNorm + N_E;
  float* pVal = zNorm + N_ROWS;
  int* pIdx = (int*)(pVal + (size_t)NPART * N_ROWS);

  k_prep<<<ZB_Z + EB_E, 256, 0, stream>>>(
      z, E, Ah, Al, Bh, Bl, eNorm, zNorm, out_loss);
  k_scores_mfma<<<dim3(N_ROWS / 128, N_E / 128), 256, 0, stream>>>(
      Ah, Al, Bh, Bl, eNorm, zNorm, pVal, pIdx);
  k_post<<<N_ROWS / 32, 256, 0, stream>>>(pVal, pIdx, z, E, out, out_loss, out_idx);
}